// Round 6
// baseline (612.033 us; speedup 1.0000x reference)
//
#include <hip/hip_runtime.h>
#include <cmath>

#define NT    8192      // B*N tokens
#define DIM_  1024
#define EXP_  7168
#define CD_   5120      // concat dim (4096 mlp + 1024 attn)
#define OD_   2048

typedef __attribute__((ext_vector_type(8))) short short8;
typedef __attribute__((ext_vector_type(4))) float f32x4;
typedef __attribute__((ext_vector_type(4))) unsigned short ushort4_t;

__device__ __forceinline__ unsigned short f2bf(float f) {
  union { float f; unsigned u; } v; v.f = f;
  return (unsigned short)((v.u + 0x7FFFu + ((v.u >> 16) & 1u)) >> 16);
}
__device__ __forceinline__ float bf2f(unsigned short u) {
  union { unsigned u; float f; } v; v.u = ((unsigned)u) << 16;
  return v.f;
}

#define MFMA16(a, b, c) __builtin_amdgcn_mfma_f32_16x16x32_bf16(a, b, c, 0, 0, 0)

// ---------------- fp32 -> bf16 convert ----------------
__global__ __launch_bounds__(256) void cvt_bf16(const float* __restrict__ in,
                                                unsigned short* __restrict__ out, int n) {
  int i = (blockIdx.x * 256 + threadIdx.x) * 4;
  if (i >= n) return;
  float4 v = *(const float4*)(in + i);
  ushort4_t o;
  o[0] = f2bf(v.x); o[1] = f2bf(v.y); o[2] = f2bf(v.z); o[3] = f2bf(v.w);
  *(ushort4_t*)(out + i) = o;
}

// ---------------- LN1 + expert input mask -> xn bf16 ----------------
__global__ __launch_bounds__(256) void ln1_kernel(const float* __restrict__ x,
    const float* __restrict__ w, const float* __restrict__ b,
    const int* __restrict__ emask, unsigned short* __restrict__ xn) {
  int wave = threadIdx.x >> 6, lane = threadIdx.x & 63;
  int t = blockIdx.x * 4 + wave;
  const float* xt = x + (size_t)t * DIM_;
  float4 v[4];
  float s = 0.f, s2 = 0.f;
#pragma unroll
  for (int i = 0; i < 4; i++) {
    v[i] = *(const float4*)(xt + i * 256 + lane * 4);
    s  += v[i].x + v[i].y + v[i].z + v[i].w;
    s2 += v[i].x * v[i].x + v[i].y * v[i].y + v[i].z * v[i].z + v[i].w * v[i].w;
  }
#pragma unroll
  for (int o = 1; o < 64; o <<= 1) { s += __shfl_xor(s, o); s2 += __shfl_xor(s2, o); }
  float mu = s * (1.f / 1024.f);
  float rs = rsqrtf(s2 * (1.f / 1024.f) - mu * mu + 1e-5f);
  int din = 1024 >> (3 - emask[t]);
  unsigned short* ot = xn + (size_t)t * DIM_;
#pragma unroll
  for (int i = 0; i < 4; i++) {
    int c0 = i * 256 + lane * 4;
    float fv[4] = { v[i].x, v[i].y, v[i].z, v[i].w };
    ushort4_t o;
#pragma unroll
    for (int j = 0; j < 4; j++) {
      int c = c0 + j;
      float val = (c < din) ? (fv[j] - mu) * rs * w[c] + b[c] : 0.f;
      o[j] = f2bf(val);
    }
    *(ushort4_t*)(ot + c0) = o;
  }
}

// ---------------- 128x128 bf16 GEMM, TLP-first (3 blocks/CU) ----------------
// 256 threads / 4 waves (2M x 2N), wave owns 64x64, acc[4][4] (64 AGPR).
// BK=32, double-buffered 32 KiB static LDS -> 3 co-resident blocks per CU;
// per-SIMD: 3 waves from 3 INDEPENDENT barrier domains (stalls overlap).
// LDS layout per slot [A|B: 128 rows x 32 k]: 64 superrows of 128 B, superrow s
// packs rows {2s,2s+1} as 8x16B chunks, phys chunk = logical ^ (s&7)
//   -> wave-read = 2-way bank conflict (free, m136); gload_lds dest stays linear
//   with the inverse swizzle applied to the GLOBAL source address (rule #21).
// K-loop per iter t (slot c=t&1): LDFRAG(c); lgkmcnt(0); barrier;
//   STAGE(t+2 -> c); 16 MFMA; vmcnt(4) [counted: drains tile t+1, cover ~1.5 iters];
//   barrier.
// EPI==1: expand epilogue (q scaled head-major / kv / gelu->concat)
// EPI==2: contract epilogue (+bias -> cy bf16)
template <int EPI, int KK, int NBN>
__global__ __launch_bounds__(256, 3) void gemm_dp(
    const unsigned short* __restrict__ A, const unsigned short* __restrict__ W,
    const float* __restrict__ bias, unsigned short* __restrict__ out0,
    unsigned short* __restrict__ out1, unsigned short* __restrict__ out2) {
  __shared__ unsigned short lds[16384];          // 32 KiB: As[2][4096] | Bs[2][4096]
  unsigned short* As = lds;
  unsigned short* Bs = lds + 8192;
  const int tid = threadIdx.x;
  const int lane = tid & 63;
  const int wave = tid >> 6;       // 0..3
  const int wm = wave >> 1, wn = wave & 1;
  const int lg = lane >> 4, lr = lane & 15;
  constexpr int NTILES = KK / 32;

  // T1: bijective XCD swizzle (grid % 8 == 0 for both shapes)
  int cpx = (int)gridDim.x >> 3;
  int lid = ((int)blockIdx.x & 7) * cpx + ((int)blockIdx.x >> 3);
  int bm = lid / NBN, bn = lid % NBN;
  int m0 = bm * 128, n0 = bn * 128;

  // staging source map (inverse of the superrow XOR swizzle), 2 instr per matrix:
  // global chunk g = i*256+tid; s=g>>3; pc=g&7; lc=pc^(s&7); row=2s+(lc>>2); kc=lc&3
  const int s0g = tid >> 3,        s1g = (256 + tid) >> 3;
  const int lc0 = (tid & 7) ^ (s0g & 7), lc1 = (tid & 7) ^ (s1g & 7);
  const int row0 = 2 * s0g + (lc0 >> 2), kc0 = lc0 & 3;
  const int row1 = 2 * s1g + (lc1 >> 2), kc1 = lc1 & 3;
  const unsigned short* aS0 = A + (size_t)(m0 + row0) * KK + kc0 * 8;
  const unsigned short* aS1 = A + (size_t)(m0 + row1) * KK + kc1 * 8;
  const unsigned short* bS0 = W + (size_t)(n0 + row0) * KK + kc0 * 8;
  const unsigned short* bS1 = W + (size_t)(n0 + row1) * KK + kc1 * 8;

#define GLD(SRC, DST)                                                                \
  __builtin_amdgcn_global_load_lds(                                                  \
      (const __attribute__((address_space(1))) void*)(SRC),                          \
      (__attribute__((address_space(3))) void*)(DST), 16, 0, 0)
#define STAGE(T, SLOT) {                                                             \
    GLD(aS0 + (size_t)(T) * 32, As + (SLOT) * 4096 + tid * 8);                       \
    GLD(aS1 + (size_t)(T) * 32, As + (SLOT) * 4096 + 2048 + tid * 8);                \
    GLD(bS0 + (size_t)(T) * 32, Bs + (SLOT) * 4096 + tid * 8);                       \
    GLD(bS1 + (size_t)(T) * 32, Bs + (SLOT) * 4096 + 2048 + tid * 8);                \
  }

  // fragment-read bases: row r -> superrow r>>1; byte = (r>>1)*128 +
  //   (((r&1)*4+lg)^((r>>1)&7))*16 ; r = (wm|wn)*64 + {mi|ni}*16 + lr
  const int fb = (lr >> 1) * 128 + ((((lr & 1) << 2) + lg) ^ ((lr >> 1) & 7)) * 16;
  const char* apb = (const char*)As + wm * 4096 + fb;
  const char* bpb = (const char*)Bs + wn * 4096 + fb;

  short8 afr[4], bfr[4];
#define LDFRAG(C)                                                                    \
  _Pragma("unroll") for (int mi = 0; mi < 4; mi++)                                   \
    afr[mi] = *(const short8*)(apb + (C) * 8192 + mi * 1024);                        \
  _Pragma("unroll") for (int ni = 0; ni < 4; ni++)                                   \
    bfr[ni] = *(const short8*)(bpb + (C) * 8192 + ni * 1024);

  f32x4 acc[4][4];
  f32x4 zf = { 0.f, 0.f, 0.f, 0.f };
#pragma unroll
  for (int i = 0; i < 4; i++)
#pragma unroll
    for (int j = 0; j < 4; j++) acc[i][j] = zf;

  // prologue: stage tiles 0 and 1; drain tile 0 (counted)
  STAGE(0, 0)
  STAGE(1, 1)
  asm volatile("s_waitcnt vmcnt(4)" ::: "memory");
  __builtin_amdgcn_s_barrier();

#pragma unroll 1
  for (int t = 0; t < NTILES; ++t) {
    const int c = t & 1;
    LDFRAG(c)
    asm volatile("s_waitcnt lgkmcnt(0)" ::: "memory");
    __builtin_amdgcn_sched_barrier(0);
    __builtin_amdgcn_s_barrier();              // all waves' reads of slot c done
    const int t2 = (t + 2 < NTILES) ? t + 2 : t;   // tail: benign same-data restage
    STAGE(t2, c)
    __builtin_amdgcn_s_setprio(1);
#pragma unroll
    for (int mi = 0; mi < 4; mi++)
#pragma unroll
      for (int ni = 0; ni < 4; ni++)
        acc[mi][ni] = MFMA16(afr[mi], bfr[ni], acc[mi][ni]);
    __builtin_amdgcn_s_setprio(0);
    asm volatile("s_waitcnt vmcnt(4)" ::: "memory");   // drain tile t+1 (counted)
    __builtin_amdgcn_s_barrier();
  }
  asm volatile("s_waitcnt vmcnt(0)" ::: "memory");

  // epilogue: grow = m0 + wm*64 + mi*16 + lg*4 + r ; gcol = n0 + wn*64 + ni*16 + lr
#pragma unroll
  for (int mi = 0; mi < 4; mi++) {
#pragma unroll
    for (int ni = 0; ni < 4; ni++) {
#pragma unroll
      for (int r = 0; r < 4; r++) {
        int grow = m0 + wm * 64 + mi * 16 + lg * 4 + r;
        int gcol = n0 + wn * 64 + ni * 16 + lr;
        float v = acc[mi][ni][r];
        if constexpr (EPI == 1) {
          float bv = bias[gcol & 4095];
          v += (gcol < 4096) ? bv : 0.f;
          if (gcol < 1024) {
            int bb = grow >> 10, n = grow & 1023, h = gcol >> 6, d = gcol & 63;
            out0[(((size_t)(bb * 16 + h) * 1024 + n) << 6) + d] = f2bf(v * 0.125f);
          } else if (gcol < 3072) {
            out1[(size_t)grow * OD_ + (gcol - 1024)] = f2bf(v);
          } else {
            float g = 0.5f * v * (1.f + erff(v * 0.70710678f));
            out2[(size_t)grow * CD_ + (gcol - 3072)] = f2bf(g);
          }
        } else {
          v += bias[gcol];
          out0[(size_t)grow * OD_ + gcol] = f2bf(v);
        }
      }
    }
  }
#undef GLD
#undef STAGE
#undef LDFRAG
}

// ---------------- LN2 over 2048 -> k (head-major bf16), v (row-major bf16) ------
__global__ __launch_bounds__(256) void ln2_kernel(const unsigned short* __restrict__ kv,
    const float* __restrict__ w, const float* __restrict__ b,
    unsigned short* __restrict__ kb, unsigned short* __restrict__ vrm) {
  int wave = threadIdx.x >> 6, lane = threadIdx.x & 63;
  int t = blockIdx.x * 4 + wave;
  const unsigned short* p = kv + (size_t)t * OD_;
  float vals[4][8];
  float s = 0.f, s2 = 0.f;
#pragma unroll
  for (int i = 0; i < 4; i++) {
    short8 v = *(const short8*)(p + i * 512 + lane * 8);
#pragma unroll
    for (int j = 0; j < 8; j++) {
      float f = bf2f((unsigned short)v[j]);
      vals[i][j] = f; s += f; s2 += f * f;
    }
  }
#pragma unroll
  for (int o = 1; o < 64; o <<= 1) { s += __shfl_xor(s, o); s2 += __shfl_xor(s2, o); }
  float mu = s * (1.f / 2048.f);
  float rs = rsqrtf(s2 * (1.f / 2048.f) - mu * mu + 1e-5f);
  int bidx = t >> 10, n = t & 1023;
#pragma unroll
  for (int i = 0; i < 4; i++) {
    int c0 = i * 512 + lane * 8;
    short8 o8;
#pragma unroll
    for (int j = 0; j < 8; j++) {
      int c = c0 + j;
      o8[j] = (short)f2bf((vals[i][j] - mu) * rs * w[c] + b[c]);
    }
    if (c0 < 1024) {
      int h = c0 >> 6, d = c0 & 63;
      *(short8*)(kb + (((size_t)(bidx * 16 + h) * 1024 + n) << 6) + d) = o8;
    } else {
      *(short8*)(vrm + (size_t)t * 1024 + (c0 - 1024)) = o8;
    }
  }
}

// ---------------- V transpose: [b,n,h*64+d] -> [b,h,d,n] ----------------
__global__ __launch_bounds__(256) void transpose_v(const unsigned short* __restrict__ vrm,
                                                   unsigned short* __restrict__ vt) {
  int bh = blockIdx.x >> 4;
  int nblk = (blockIdx.x & 15) * 64;
  int b = bh >> 4, h = bh & 15;
  __shared__ unsigned short tile[64][65];
  int tid = threadIdx.x;
  int i = tid >> 2;
  int d0 = (tid & 3) * 16;
  const unsigned short* src = vrm + ((size_t)(b * 1024 + nblk + i)) * 1024 + h * 64 + d0;
  short8 v0 = *(const short8*)(src);
  short8 v1 = *(const short8*)(src + 8);
#pragma unroll
  for (int j = 0; j < 8; j++) {
    tile[d0 + j][i] = (unsigned short)v0[j];
    tile[d0 + 8 + j][i] = (unsigned short)v1[j];
  }
  __syncthreads();
  int d = tid >> 2;
  int i0 = (tid & 3) * 16;
  unsigned short* dst = vt + ((size_t)bh * 64 + d) * 1024 + nblk + i0;
  short8 o0, o1;
#pragma unroll
  for (int j = 0; j < 8; j++) { o0[j] = (short)tile[d][i0 + j]; o1[j] = (short)tile[d][i0 + 8 + j]; }
  *(short8*)dst = o0;
  *(short8*)(dst + 8) = o1;
}

// ---------------- flash attention: 1 wave, 32 q-rows, KV tiles of 32 ----------------
__global__ __launch_bounds__(64) void attn_kernel(const unsigned short* __restrict__ q,
    const unsigned short* __restrict__ k, const unsigned short* __restrict__ vt,
    unsigned short* __restrict__ concat) {
  int bh = blockIdx.x >> 5;
  int q0 = (blockIdx.x & 31) * 32;
  int lane = threadIdx.x;
  int lg = lane >> 4, lr = lane & 15;
  __shared__ unsigned short plds[2][512];
  const unsigned short* qp = q + (size_t)bh * (1024 * 64);
  const unsigned short* kp = k + (size_t)bh * (1024 * 64);
  const unsigned short* vp = vt + (size_t)bh * (64 * 1024);
  short8 qf[2][2];
#pragma unroll
  for (int rb = 0; rb < 2; rb++)
#pragma unroll
    for (int c = 0; c < 2; c++)
      qf[rb][c] = *(const short8*)(qp + (q0 + rb * 16 + lr) * 64 + c * 32 + lg * 8);
  f32x4 zf = { 0.f, 0.f, 0.f, 0.f };
  f32x4 o[2][4];
  float m[2][4], l[2][4];
#pragma unroll
  for (int rb = 0; rb < 2; rb++) {
#pragma unroll
    for (int r = 0; r < 4; r++) { m[rb][r] = -1e30f; l[rb][r] = 0.f; }
#pragma unroll
    for (int nb = 0; nb < 4; nb++) o[rb][nb] = zf;
  }
  for (int kt = 0; kt < 1024; kt += 32) {
    f32x4 s[2][2];
    s[0][0] = zf; s[0][1] = zf; s[1][0] = zf; s[1][1] = zf;
#pragma unroll
    for (int h2 = 0; h2 < 2; h2++) {
      short8 kf0 = *(const short8*)(kp + (kt + h2 * 16 + lr) * 64 + lg * 8);
      short8 kf1 = *(const short8*)(kp + (kt + h2 * 16 + lr) * 64 + 32 + lg * 8);
      s[0][h2] = MFMA16(qf[0][0], kf0, s[0][h2]);
      s[0][h2] = MFMA16(qf[0][1], kf1, s[0][h2]);
      s[1][h2] = MFMA16(qf[1][0], kf0, s[1][h2]);
      s[1][h2] = MFMA16(qf[1][1], kf1, s[1][h2]);
    }
    __syncthreads();  // WAR: previous iteration's P reads complete
#pragma unroll
    for (int rb = 0; rb < 2; rb++) {
      float mx[4], rsum[4];
#pragma unroll
      for (int r = 0; r < 4; r++) mx[r] = fmaxf(s[rb][0][r], s[rb][1][r]);
#pragma unroll
      for (int ofs = 1; ofs < 16; ofs <<= 1)
#pragma unroll
        for (int r = 0; r < 4; r++) mx[r] = fmaxf(mx[r], __shfl_xor(mx[r], ofs));
#pragma unroll
      for (int r = 0; r < 4; r++) {
        float mn = fmaxf(m[rb][r], mx[r]);
        float al = __expf(m[rb][r] - mn);
        float p0 = __expf(s[rb][0][r] - mn);
        float p1 = __expf(s[rb][1][r] - mn);
        m[rb][r] = mn;
        plds[rb][(lg * 4 + r) * 32 + lr] = f2bf(p0);
        plds[rb][(lg * 4 + r) * 32 + 16 + lr] = f2bf(p1);
        rsum[r] = p0 + p1;
        l[rb][r] *= al;
#pragma unroll
        for (int nb = 0; nb < 4; nb++) o[rb][nb][r] *= al;
      }
#pragma unroll
      for (int ofs = 1; ofs < 16; ofs <<= 1)
#pragma unroll
        for (int r = 0; r < 4; r++) rsum[r] += __shfl_xor(rsum[r], ofs);
#pragma unroll
      for (int r = 0; r < 4; r++) l[rb][r] += rsum[r];
    }
    __syncthreads();  // RAW: P visible
    short8 pf0 = *(const short8*)(&plds[0][lr * 32 + lg * 8]);
    short8 pf1 = *(const short8*)(&plds[1][lr * 32 + lg * 8]);
#pragma unroll
    for (int nb = 0; nb < 4; nb++) {
      short8 vf = *(const short8*)(vp + (nb * 16 + lr) * 1024 + kt + lg * 8);
      o[0][nb] = MFMA16(pf0, vf, o[0][nb]);
      o[1][nb] = MFMA16(pf1, vf, o[1][nb]);
    }
  }
  int b = bh >> 4, h = bh & 15;
#pragma unroll
  for (int rb = 0; rb < 2; rb++)
#pragma unroll
    for (int r = 0; r < 4; r++) {
      int n = q0 + rb * 16 + lg * 4 + r;
      size_t t = (size_t)b * 1024 + n;
      float inv = 1.f / l[rb][r];
#pragma unroll
      for (int nb = 0; nb < 4; nb++)
        concat[t * CD_ + 4096 + h * 64 + nb * 16 + lr] = f2bf(o[rb][nb][r] * inv);
    }
}

// ---------------- final epilogue: mask, residual, expert combine ----------------
__global__ __launch_bounds__(256) void final_epi(const unsigned short* __restrict__ cy,
    const float* __restrict__ x, const float* __restrict__ probs,
    const int* __restrict__ emask, float* __restrict__ out) {
  int t = blockIdx.x;
  int c = threadIdx.x * 4;
  int dout = 2048 >> (3 - emask[t]);
  float p = probs[t];
  const unsigned short* cyt = cy + (size_t)t * OD_;
  ushort4_t mv = *(const ushort4_t*)(cyt + c);
  ushort4_t av = *(const ushort4_t*)(cyt + 1024 + c);
  float4 xv = *(const float4*)(x + (size_t)t * 1024 + c);
  float xa[4] = { xv.x, xv.y, xv.z, xv.w };
  float4 o;
  float oa[4];
#pragma unroll
  for (int j = 0; j < 4; j++) {
    float mlp = ((c + j) < dout ? bf2f(mv[j]) : 0.f) + xa[j];
    float att = ((1024 + c + j) < dout ? bf2f(av[j]) : 0.f) + xa[j];
    oa[j] = att + p * mlp;
  }
  o.x = oa[0]; o.y = oa[1]; o.z = oa[2]; o.w = oa[3];
  *(float4*)(out + (size_t)t * 1024 + c) = o;
}

extern "C" void kernel_launch(void* const* d_in, const int* in_sizes, int n_in,
                              void* d_out, int out_size, void* d_ws, size_t ws_size,
                              hipStream_t stream) {
  const float* x        = (const float*)d_in[0];
  const float* probs    = (const float*)d_in[1];
  const float* we       = (const float*)d_in[2];
  const float* mlp_bias = (const float*)d_in[3];
  const float* wc       = (const float*)d_in[4];
  const float* cbias    = (const float*)d_in[5];
  const float* n1w      = (const float*)d_in[6];
  const float* n1b      = (const float*)d_in[7];
  const float* n2w      = (const float*)d_in[8];
  const float* n2b      = (const float*)d_in[9];
  const int*   emask    = (const int*)d_in[10];
  float* out = (float*)d_out;

  char* ws = (char*)d_ws;
  size_t off = 0;
  auto alloc = [&](size_t bytes) {
    char* p = ws + off;
    off += (bytes + 255) & ~(size_t)255;
    return p;
  };
  unsigned short* we_bf = (unsigned short*)alloc((size_t)EXP_ * DIM_ * 2);
  unsigned short* wc_bf = (unsigned short*)alloc((size_t)OD_ * CD_ * 2);
  unsigned short* xn    = (unsigned short*)alloc((size_t)NT * DIM_ * 2);  // reused as vrm
  unsigned short* qb    = (unsigned short*)alloc((size_t)NT * DIM_ * 2);
  unsigned short* kv    = (unsigned short*)alloc((size_t)NT * OD_ * 2);   // reused as cy
  unsigned short* kb    = (unsigned short*)alloc((size_t)NT * DIM_ * 2);
  unsigned short* vt    = (unsigned short*)alloc((size_t)NT * DIM_ * 2);
  unsigned short* cc    = (unsigned short*)alloc((size_t)NT * CD_ * 2);
  unsigned short* vrm = xn;
  unsigned short* cy  = kv;
  if (off > ws_size) return;  // insufficient workspace -> visible failure, no OOB

  cvt_bf16<<<7168, 256, 0, stream>>>(we, we_bf, EXP_ * DIM_);
  cvt_bf16<<<10240, 256, 0, stream>>>(wc, wc_bf, OD_ * CD_);
  ln1_kernel<<<2048, 256, 0, stream>>>(x, n1w, n1b, emask, xn);
  gemm_dp<1, 1024, 56><<<3584, 256, 0, stream>>>(xn, we_bf, mlp_bias, qb, kv, cc);
  ln2_kernel<<<2048, 256, 0, stream>>>(kv, n2w, n2b, kb, vrm);
  transpose_v<<<2048, 256, 0, stream>>>(vrm, vt);
  attn_kernel<<<4096, 64, 0, stream>>>(qb, kb, vt, cc);
  gemm_dp<2, 5120, 16><<<1024, 256, 0, stream>>>(cc, wc_bf, cbias, cy, nullptr, nullptr);
  final_epi<<<8192, 256, 0, stream>>>(cy, x, probs, emask, out);
}

// Round 7
// 579.355 us; speedup vs baseline: 1.0564x; 1.0564x over previous
//
#include <hip/hip_runtime.h>
#include <cmath>

#define NT    8192      // B*N tokens
#define DIM_  1024
#define EXP_  7168
#define CD_   5120      // concat dim (4096 mlp + 1024 attn)
#define OD_   2048
#define MPAD  8704      // 68 row-tiles of 128 (8192 + worst-case group padding)
#define NRT   68        // row tiles in sorted/padded space

typedef __attribute__((ext_vector_type(8))) short short8;
typedef __attribute__((ext_vector_type(4))) float f32x4;
typedef __attribute__((ext_vector_type(4))) unsigned short ushort4_t;

__device__ __forceinline__ unsigned short f2bf(float f) {
  union { float f; unsigned u; } v; v.f = f;
  return (unsigned short)((v.u + 0x7FFFu + ((v.u >> 16) & 1u)) >> 16);
}
__device__ __forceinline__ float bf2f(unsigned short u) {
  union { unsigned u; float f; } v; v.u = ((unsigned)u) << 16;
  return v.f;
}

#define MFMA16(a, b, c) __builtin_amdgcn_mfma_f32_16x16x32_bf16(a, b, c, 0, 0, 0)

// ======== expert sort: count -> scan -> fill -> scatter (all tiny) ========
// desc layout (ints): [0..3]=base[e] (padded row start), [4..7]=cnt[e],
//                     [8..8+NRT)=tileExpert[r] (-1 = pad tile),
//                     [76..76+128)=blockOff[32][4]
__global__ __launch_bounds__(256) void count_experts(const int* __restrict__ em,
                                                     int* __restrict__ blockCnt) {
  __shared__ int h[4];
  int tid = threadIdx.x;
  if (tid < 4) h[tid] = 0;
  __syncthreads();
  atomicAdd(&h[em[blockIdx.x * 256 + tid]], 1);
  __syncthreads();
  if (tid < 4) blockCnt[blockIdx.x * 4 + tid] = h[tid];
}

__global__ void scan_make(const int* __restrict__ blockCnt, int* __restrict__ desc) {
  if (threadIdx.x != 0) return;
  int cnt[4] = {0, 0, 0, 0};
  for (int b = 0; b < 32; b++)
    for (int e = 0; e < 4; e++) cnt[e] += blockCnt[b * 4 + e];
  int base[4]; int acc = 0;
  for (int e = 0; e < 4; e++) { base[e] = acc; acc += ((cnt[e] + 127) >> 7) << 7; }
  for (int e = 0; e < 4; e++) { desc[e] = base[e]; desc[4 + e] = cnt[e]; }
  for (int r = 0; r < NRT; r++) {
    int te = -1;
    for (int e = 0; e < 4; e++) {
      int lo = base[e] >> 7;
      int hi = (base[e] + (((cnt[e] + 127) >> 7) << 7)) >> 7;
      if (r >= lo && r < hi) te = e;
    }
    desc[8 + r] = te;
  }
  int run[4];
  for (int e = 0; e < 4; e++) run[e] = base[e];
  for (int b = 0; b < 32; b++)
    for (int e = 0; e < 4; e++) { desc[76 + b * 4 + e] = run[e]; run[e] += blockCnt[b * 4 + e]; }
}

__global__ __launch_bounds__(256) void fill_perm(int* __restrict__ perm) {
  int i = blockIdx.x * 256 + threadIdx.x;
  if (i < MPAD) perm[i] = -1;
}

__global__ __launch_bounds__(256) void scatter_perm(const int* __restrict__ em,
    const int* __restrict__ desc, int* __restrict__ perm, int* __restrict__ pos) {
  __shared__ int wsum[4][4];  // [wave][expert]
  int tid = threadIdx.x;
  int wv = tid >> 6, ln = tid & 63;
  int t = blockIdx.x * 256 + tid;
  int e = em[t];
  int wrank = 0;
#pragma unroll
  for (int k = 0; k < 4; k++) {
    unsigned long long m = __ballot(e == k);
    if (ln == 0) wsum[wv][k] = __popcll(m);
    if (e == k) wrank = __popcll(m & ((1ull << ln) - 1ull));
  }
  __syncthreads();
  int off = desc[76 + blockIdx.x * 4 + e];
  for (int w = 0; w < wv; w++) off += wsum[w][e];
  int p = off + wrank;
  perm[p] = t;
  pos[t] = p;
}

// ---------------- fp32 -> bf16 convert ----------------
__global__ __launch_bounds__(256) void cvt_bf16(const float* __restrict__ in,
                                                unsigned short* __restrict__ out, int n) {
  int i = (blockIdx.x * 256 + threadIdx.x) * 4;
  if (i >= n) return;
  float4 v = *(const float4*)(in + i);
  ushort4_t o;
  o[0] = f2bf(v.x); o[1] = f2bf(v.y); o[2] = f2bf(v.z); o[3] = f2bf(v.w);
  *(ushort4_t*)(out + i) = o;
}

// ---------------- LN1 + expert input mask -> xn bf16 (SORTED rows) ----------------
__global__ __launch_bounds__(256) void ln1_kernel(const float* __restrict__ x,
    const float* __restrict__ w, const float* __restrict__ b,
    const int* __restrict__ emask, const int* __restrict__ pos,
    unsigned short* __restrict__ xn) {
  int wave = threadIdx.x >> 6, lane = threadIdx.x & 63;
  int t = blockIdx.x * 4 + wave;
  const float* xt = x + (size_t)t * DIM_;
  float4 v[4];
  float s = 0.f, s2 = 0.f;
#pragma unroll
  for (int i = 0; i < 4; i++) {
    v[i] = *(const float4*)(xt + i * 256 + lane * 4);
    s  += v[i].x + v[i].y + v[i].z + v[i].w;
    s2 += v[i].x * v[i].x + v[i].y * v[i].y + v[i].z * v[i].z + v[i].w * v[i].w;
  }
#pragma unroll
  for (int o = 1; o < 64; o <<= 1) { s += __shfl_xor(s, o); s2 += __shfl_xor(s2, o); }
  float mu = s * (1.f / 1024.f);
  float rs = rsqrtf(s2 * (1.f / 1024.f) - mu * mu + 1e-5f);
  int din = 1024 >> (3 - emask[t]);
  unsigned short* ot = xn + (size_t)pos[t] * DIM_;
#pragma unroll
  for (int i = 0; i < 4; i++) {
    int c0 = i * 256 + lane * 4;
    float fv[4] = { v[i].x, v[i].y, v[i].z, v[i].w };
    ushort4_t o;
#pragma unroll
    for (int j = 0; j < 4; j++) {
      int c = c0 + j;
      float val = (c < din) ? (fv[j] - mu) * rs * w[c] + b[c] : 0.f;
      o[j] = f2bf(val);
    }
    *(ushort4_t*)(ot + c0) = o;
  }
}

// ---------------- grouped 128x128 bf16 GEMM (R6 gemm_dp body, expert-aware) -----
// EPI==1: K = 128<<e per row-tile; scatter q/kv to original tokens, cc stays sorted.
// EPI==2: full K; skip col-tiles >= dout=256<<e; cy stays sorted.
template <int EPI, int KK, int NBN>
__global__ __launch_bounds__(256, 3) void gemm_grp(
    const unsigned short* __restrict__ A, const unsigned short* __restrict__ W,
    const float* __restrict__ bias, const int* __restrict__ tdesc,
    const int* __restrict__ perm, unsigned short* __restrict__ out0,
    unsigned short* __restrict__ out1, unsigned short* __restrict__ out2) {
  __shared__ unsigned short lds[16384];          // 32 KiB: As[2][4096] | Bs[2][4096]
  unsigned short* As = lds;
  unsigned short* Bs = lds + 8192;
  const int r = blockIdx.y;
  const int e = tdesc[8 + r];
  if (e < 0) return;                             // pad tile (uniform exit)
  int ntiles;
  if constexpr (EPI == 1) ntiles = 4 << e;       // K = 128<<e, BK=32
  else                    ntiles = KK / 32;

  const int tid = threadIdx.x;
  const int lane = tid & 63;
  const int wave = tid >> 6;       // 0..3
  const int wm = wave >> 1, wn = wave & 1;
  const int lg = lane >> 4, lr = lane & 15;

  // XCD swizzle on col dim (NBN % 8 == 0)
  constexpr int CPX = NBN >> 3;
  const int bx = (int)blockIdx.x;
  const int bn = (bx & 7) * CPX + (bx >> 3);
  const int n0 = bn * 128;
  if constexpr (EPI == 2) {
    if (n0 >= (256 << e)) return;                // masked-out output cols (uniform)
  }
  const int m0 = r * 128;

  // staging source map (inverse of superrow XOR swizzle) — verbatim from R6
  const int s0g = tid >> 3,        s1g = (256 + tid) >> 3;
  const int lc0 = (tid & 7) ^ (s0g & 7), lc1 = (tid & 7) ^ (s1g & 7);
  const int row0 = 2 * s0g + (lc0 >> 2), kc0 = lc0 & 3;
  const int row1 = 2 * s1g + (lc1 >> 2), kc1 = lc1 & 3;
  const unsigned short* aS0 = A + (size_t)(m0 + row0) * KK + kc0 * 8;
  const unsigned short* aS1 = A + (size_t)(m0 + row1) * KK + kc1 * 8;
  const unsigned short* bS0 = W + (size_t)(n0 + row0) * KK + kc0 * 8;
  const unsigned short* bS1 = W + (size_t)(n0 + row1) * KK + kc1 * 8;

#define GLD(SRC, DST)                                                                \
  __builtin_amdgcn_global_load_lds(                                                  \
      (const __attribute__((address_space(1))) void*)(SRC),                          \
      (__attribute__((address_space(3))) void*)(DST), 16, 0, 0)
#define STAGE(T, SLOT) {                                                             \
    GLD(aS0 + (size_t)(T) * 32, As + (SLOT) * 4096 + tid * 8);                       \
    GLD(aS1 + (size_t)(T) * 32, As + (SLOT) * 4096 + 2048 + tid * 8);                \
    GLD(bS0 + (size_t)(T) * 32, Bs + (SLOT) * 4096 + tid * 8);                       \
    GLD(bS1 + (size_t)(T) * 32, Bs + (SLOT) * 4096 + 2048 + tid * 8);                \
  }

  const int fb = (lr >> 1) * 128 + ((((lr & 1) << 2) + lg) ^ ((lr >> 1) & 7)) * 16;
  const char* apb = (const char*)As + wm * 4096 + fb;
  const char* bpb = (const char*)Bs + wn * 4096 + fb;

  short8 afr[4], bfr[4];
#define LDFRAG(C)                                                                    \
  _Pragma("unroll") for (int mi = 0; mi < 4; mi++)                                   \
    afr[mi] = *(const short8*)(apb + (C) * 8192 + mi * 1024);                        \
  _Pragma("unroll") for (int ni = 0; ni < 4; ni++)                                   \
    bfr[ni] = *(const short8*)(bpb + (C) * 8192 + ni * 1024);

  f32x4 acc[4][4];
  f32x4 zf = { 0.f, 0.f, 0.f, 0.f };
#pragma unroll
  for (int i = 0; i < 4; i++)
#pragma unroll
    for (int j = 0; j < 4; j++) acc[i][j] = zf;

  STAGE(0, 0)
  STAGE(1, 1)
  asm volatile("s_waitcnt vmcnt(4)" ::: "memory");
  __builtin_amdgcn_s_barrier();

#pragma unroll 1
  for (int t = 0; t < ntiles; ++t) {
    const int c = t & 1;
    LDFRAG(c)
    asm volatile("s_waitcnt lgkmcnt(0)" ::: "memory");
    __builtin_amdgcn_sched_barrier(0);
    __builtin_amdgcn_s_barrier();
    const int t2 = (t + 2 < ntiles) ? t + 2 : t;
    STAGE(t2, c)
    __builtin_amdgcn_s_setprio(1);
#pragma unroll
    for (int mi = 0; mi < 4; mi++)
#pragma unroll
      for (int ni = 0; ni < 4; ni++)
        acc[mi][ni] = MFMA16(afr[mi], bfr[ni], acc[mi][ni]);
    __builtin_amdgcn_s_setprio(0);
    asm volatile("s_waitcnt vmcnt(4)" ::: "memory");
    __builtin_amdgcn_s_barrier();
  }
  asm volatile("s_waitcnt vmcnt(0)" ::: "memory");

  // epilogue: grow (sorted row) = m0 + wm*64 + mi*16 + lg*4 + r ; gcol = n0 + wn*64 + ni*16 + lr
#pragma unroll
  for (int mi = 0; mi < 4; mi++) {
#pragma unroll
    for (int ni = 0; ni < 4; ni++) {
#pragma unroll
      for (int rr = 0; rr < 4; rr++) {
        int grow = m0 + wm * 64 + mi * 16 + lg * 4 + rr;
        int gcol = n0 + wn * 64 + ni * 16 + lr;
        float v = acc[mi][ni][rr];
        if constexpr (EPI == 1) {
          int tk = perm[grow];                 // original token (-1 = pad row)
          float bv = bias[gcol & 4095];
          v += (gcol < 4096) ? bv : 0.f;
          if (gcol < 1024) {
            if (tk >= 0) {
              int bb = tk >> 10, n = tk & 1023, h = gcol >> 6, d = gcol & 63;
              out0[(((size_t)(bb * 16 + h) * 1024 + n) << 6) + d] = f2bf(v * 0.125f);
            }
          } else if (gcol < 3072) {
            if (tk >= 0) out1[(size_t)tk * OD_ + (gcol - 1024)] = f2bf(v);
          } else {
            float g = 0.5f * v * (1.f + erff(v * 0.70710678f));
            out2[(size_t)grow * CD_ + (gcol - 3072)] = f2bf(g);   // cc stays sorted
          }
        } else {
          v += bias[gcol];
          out0[(size_t)grow * OD_ + gcol] = f2bf(v);              // cy stays sorted
        }
      }
    }
  }
#undef GLD
#undef STAGE
#undef LDFRAG
}

// ---------------- LN2 over 2048 -> k (head-major bf16), v (row-major bf16) ------
__global__ __launch_bounds__(256) void ln2_kernel(const unsigned short* __restrict__ kv,
    const float* __restrict__ w, const float* __restrict__ b,
    unsigned short* __restrict__ kb, unsigned short* __restrict__ vrm) {
  int wave = threadIdx.x >> 6, lane = threadIdx.x & 63;
  int t = blockIdx.x * 4 + wave;
  const unsigned short* p = kv + (size_t)t * OD_;
  float vals[4][8];
  float s = 0.f, s2 = 0.f;
#pragma unroll
  for (int i = 0; i < 4; i++) {
    short8 v = *(const short8*)(p + i * 512 + lane * 8);
#pragma unroll
    for (int j = 0; j < 8; j++) {
      float f = bf2f((unsigned short)v[j]);
      vals[i][j] = f; s += f; s2 += f * f;
    }
  }
#pragma unroll
  for (int o = 1; o < 64; o <<= 1) { s += __shfl_xor(s, o); s2 += __shfl_xor(s2, o); }
  float mu = s * (1.f / 2048.f);
  float rs = rsqrtf(s2 * (1.f / 2048.f) - mu * mu + 1e-5f);
  int bidx = t >> 10, n = t & 1023;
#pragma unroll
  for (int i = 0; i < 4; i++) {
    int c0 = i * 512 + lane * 8;
    short8 o8;
#pragma unroll
    for (int j = 0; j < 8; j++) {
      int c = c0 + j;
      o8[j] = (short)f2bf((vals[i][j] - mu) * rs * w[c] + b[c]);
    }
    if (c0 < 1024) {
      int h = c0 >> 6, d = c0 & 63;
      *(short8*)(kb + (((size_t)(bidx * 16 + h) * 1024 + n) << 6) + d) = o8;
    } else {
      *(short8*)(vrm + (size_t)t * 1024 + (c0 - 1024)) = o8;
    }
  }
}

// ---------------- V transpose: [b,n,h*64+d] -> [b,h,d,n] ----------------
__global__ __launch_bounds__(256) void transpose_v(const unsigned short* __restrict__ vrm,
                                                   unsigned short* __restrict__ vt) {
  int bh = blockIdx.x >> 4;
  int nblk = (blockIdx.x & 15) * 64;
  int b = bh >> 4, h = bh & 15;
  __shared__ unsigned short tile[64][65];
  int tid = threadIdx.x;
  int i = tid >> 2;
  int d0 = (tid & 3) * 16;
  const unsigned short* src = vrm + ((size_t)(b * 1024 + nblk + i)) * 1024 + h * 64 + d0;
  short8 v0 = *(const short8*)(src);
  short8 v1 = *(const short8*)(src + 8);
#pragma unroll
  for (int j = 0; j < 8; j++) {
    tile[d0 + j][i] = (unsigned short)v0[j];
    tile[d0 + 8 + j][i] = (unsigned short)v1[j];
  }
  __syncthreads();
  int d = tid >> 2;
  int i0 = (tid & 3) * 16;
  unsigned short* dst = vt + ((size_t)bh * 64 + d) * 1024 + nblk + i0;
  short8 o0, o1;
#pragma unroll
  for (int j = 0; j < 8; j++) { o0[j] = (short)tile[d][i0 + j]; o1[j] = (short)tile[d][i0 + 8 + j]; }
  *(short8*)dst = o0;
  *(short8*)(dst + 8) = o1;
}

// ---------------- flash attention: 1 wave, 32 q-rows, KV tiles of 32 ----------------
__global__ __launch_bounds__(64) void attn_kernel(const unsigned short* __restrict__ q,
    const unsigned short* __restrict__ k, const unsigned short* __restrict__ vt,
    const int* __restrict__ pos, unsigned short* __restrict__ concat) {
  int bh = blockIdx.x >> 5;
  int q0 = (blockIdx.x & 31) * 32;
  int lane = threadIdx.x;
  int lg = lane >> 4, lr = lane & 15;
  __shared__ unsigned short plds[2][512];
  const unsigned short* qp = q + (size_t)bh * (1024 * 64);
  const unsigned short* kp = k + (size_t)bh * (1024 * 64);
  const unsigned short* vp = vt + (size_t)bh * (64 * 1024);
  short8 qf[2][2];
#pragma unroll
  for (int rb = 0; rb < 2; rb++)
#pragma unroll
    for (int c = 0; c < 2; c++)
      qf[rb][c] = *(const short8*)(qp + (q0 + rb * 16 + lr) * 64 + c * 32 + lg * 8);
  f32x4 zf = { 0.f, 0.f, 0.f, 0.f };
  f32x4 o[2][4];
  float m[2][4], l[2][4];
#pragma unroll
  for (int rb = 0; rb < 2; rb++) {
#pragma unroll
    for (int r = 0; r < 4; r++) { m[rb][r] = -1e30f; l[rb][r] = 0.f; }
#pragma unroll
    for (int nb = 0; nb < 4; nb++) o[rb][nb] = zf;
  }
  for (int kt = 0; kt < 1024; kt += 32) {
    f32x4 s[2][2];
    s[0][0] = zf; s[0][1] = zf; s[1][0] = zf; s[1][1] = zf;
#pragma unroll
    for (int h2 = 0; h2 < 2; h2++) {
      short8 kf0 = *(const short8*)(kp + (kt + h2 * 16 + lr) * 64 + lg * 8);
      short8 kf1 = *(const short8*)(kp + (kt + h2 * 16 + lr) * 64 + 32 + lg * 8);
      s[0][h2] = MFMA16(qf[0][0], kf0, s[0][h2]);
      s[0][h2] = MFMA16(qf[0][1], kf1, s[0][h2]);
      s[1][h2] = MFMA16(qf[1][0], kf0, s[1][h2]);
      s[1][h2] = MFMA16(qf[1][1], kf1, s[1][h2]);
    }
    __syncthreads();
#pragma unroll
    for (int rb = 0; rb < 2; rb++) {
      float mx[4], rsum[4];
#pragma unroll
      for (int r = 0; r < 4; r++) mx[r] = fmaxf(s[rb][0][r], s[rb][1][r]);
#pragma unroll
      for (int ofs = 1; ofs < 16; ofs <<= 1)
#pragma unroll
        for (int r = 0; r < 4; r++) mx[r] = fmaxf(mx[r], __shfl_xor(mx[r], ofs));
#pragma unroll
      for (int r = 0; r < 4; r++) {
        float mn = fmaxf(m[rb][r], mx[r]);
        float al = __expf(m[rb][r] - mn);
        float p0 = __expf(s[rb][0][r] - mn);
        float p1 = __expf(s[rb][1][r] - mn);
        m[rb][r] = mn;
        plds[rb][(lg * 4 + r) * 32 + lr] = f2bf(p0);
        plds[rb][(lg * 4 + r) * 32 + 16 + lr] = f2bf(p1);
        rsum[r] = p0 + p1;
        l[rb][r] *= al;
#pragma unroll
        for (int nb = 0; nb < 4; nb++) o[rb][nb][r] *= al;
      }
#pragma unroll
      for (int ofs = 1; ofs < 16; ofs <<= 1)
#pragma unroll
        for (int r = 0; r < 4; r++) rsum[r] += __shfl_xor(rsum[r], ofs);
#pragma unroll
      for (int r = 0; r < 4; r++) l[rb][r] += rsum[r];
    }
    __syncthreads();
    short8 pf0 = *(const short8*)(&plds[0][lr * 32 + lg * 8]);
    short8 pf1 = *(const short8*)(&plds[1][lr * 32 + lg * 8]);
#pragma unroll
    for (int nb = 0; nb < 4; nb++) {
      short8 vf = *(const short8*)(vp + (nb * 16 + lr) * 1024 + kt + lg * 8);
      o[0][nb] = MFMA16(pf0, vf, o[0][nb]);
      o[1][nb] = MFMA16(pf1, vf, o[1][nb]);
    }
  }
  int b = bh >> 4, h = bh & 15;
#pragma unroll
  for (int rb = 0; rb < 2; rb++)
#pragma unroll
    for (int r = 0; r < 4; r++) {
      int n = q0 + rb * 16 + lg * 4 + r;
      int s = pos[b * 1024 + n];          // write concat at SORTED row
      float inv = 1.f / l[rb][r];
#pragma unroll
      for (int nb = 0; nb < 4; nb++)
        concat[(size_t)s * CD_ + 4096 + h * 64 + nb * 16 + lr] = f2bf(o[rb][nb][r] * inv);
    }
}

// ---------------- final epilogue: mask, residual, expert combine ----------------
__global__ __launch_bounds__(256) void final_epi(const unsigned short* __restrict__ cy,
    const float* __restrict__ x, const float* __restrict__ probs,
    const int* __restrict__ emask, const int* __restrict__ pos,
    float* __restrict__ out) {
  int t = blockIdx.x;
  int c = threadIdx.x * 4;
  int dout = 2048 >> (3 - emask[t]);
  float p = probs[t];
  const unsigned short* cyt = cy + (size_t)pos[t] * OD_;
  ushort4_t mv = *(const ushort4_t*)(cyt + c);
  ushort4_t av = *(const ushort4_t*)(cyt + 1024 + c);
  float4 xv = *(const float4*)(x + (size_t)t * 1024 + c);
  float xa[4] = { xv.x, xv.y, xv.z, xv.w };
  float4 o;
  float oa[4];
#pragma unroll
  for (int j = 0; j < 4; j++) {
    float mlp = ((c + j) < dout ? bf2f(mv[j]) : 0.f) + xa[j];
    float att = ((1024 + c + j) < dout ? bf2f(av[j]) : 0.f) + xa[j];
    oa[j] = att + p * mlp;
  }
  o.x = oa[0]; o.y = oa[1]; o.z = oa[2]; o.w = oa[3];
  *(float4*)(out + (size_t)t * 1024 + c) = o;
}

extern "C" void kernel_launch(void* const* d_in, const int* in_sizes, int n_in,
                              void* d_out, int out_size, void* d_ws, size_t ws_size,
                              hipStream_t stream) {
  const float* x        = (const float*)d_in[0];
  const float* probs    = (const float*)d_in[1];
  const float* we       = (const float*)d_in[2];
  const float* mlp_bias = (const float*)d_in[3];
  const float* wc       = (const float*)d_in[4];
  const float* cbias    = (const float*)d_in[5];
  const float* n1w      = (const float*)d_in[6];
  const float* n1b      = (const float*)d_in[7];
  const float* n2w      = (const float*)d_in[8];
  const float* n2b      = (const float*)d_in[9];
  const int*   emask    = (const int*)d_in[10];
  float* out = (float*)d_out;

  char* ws = (char*)d_ws;
  size_t off = 0;
  auto alloc = [&](size_t bytes) {
    char* p = ws + off;
    off += (bytes + 255) & ~(size_t)255;
    return p;
  };
  unsigned short* we_bf = (unsigned short*)alloc((size_t)EXP_ * DIM_ * 2);
  unsigned short* wc_bf = (unsigned short*)alloc((size_t)OD_ * CD_ * 2);
  unsigned short* xn    = (unsigned short*)alloc((size_t)MPAD * DIM_ * 2); // sorted; reused as vrm
  unsigned short* qb    = (unsigned short*)alloc((size_t)NT * DIM_ * 2);
  unsigned short* kv    = (unsigned short*)alloc((size_t)MPAD * OD_ * 2);  // orig order; reused as cy (sorted)
  unsigned short* kb    = (unsigned short*)alloc((size_t)NT * DIM_ * 2);
  unsigned short* vt    = (unsigned short*)alloc((size_t)NT * DIM_ * 2);
  unsigned short* cc    = (unsigned short*)alloc((size_t)MPAD * CD_ * 2);  // sorted
  int* blockCnt         = (int*)alloc(32 * 4 * 4);
  int* desc             = (int*)alloc(256 * 4);
  int* perm             = (int*)alloc(MPAD * 4);
  int* pos              = (int*)alloc(NT * 4);
  unsigned short* vrm = xn;
  unsigned short* cy  = kv;
  if (off > ws_size) return;  // insufficient workspace -> visible failure, no OOB

  count_experts<<<32, 256, 0, stream>>>(emask, blockCnt);
  scan_make<<<1, 64, 0, stream>>>(blockCnt, desc);
  fill_perm<<<34, 256, 0, stream>>>(perm);
  scatter_perm<<<32, 256, 0, stream>>>(emask, desc, perm, pos);

  cvt_bf16<<<7168, 256, 0, stream>>>(we, we_bf, EXP_ * DIM_);
  cvt_bf16<<<10240, 256, 0, stream>>>(wc, wc_bf, OD_ * CD_);
  ln1_kernel<<<2048, 256, 0, stream>>>(x, n1w, n1b, emask, pos, xn);
  gemm_grp<1, 1024, 56><<<dim3(56, NRT), 256, 0, stream>>>(xn, we_bf, mlp_bias, desc,
                                                           perm, qb, kv, cc);
  ln2_kernel<<<2048, 256, 0, stream>>>(kv, n2w, n2b, kb, vrm);
  transpose_v<<<2048, 256, 0, stream>>>(vrm, vt);
  attn_kernel<<<4096, 64, 0, stream>>>(qb, kb, vt, pos, cc);
  gemm_grp<2, 5120, 16><<<dim3(16, NRT), 256, 0, stream>>>(cc, wc_bf, cbias, desc,
                                                           perm, cy, nullptr, nullptr);
  final_epi<<<8192, 256, 0, stream>>>(cy, x, probs, emask, pos, out);
}

// Round 8
// 561.809 us; speedup vs baseline: 1.0894x; 1.0312x over previous
//
#include <hip/hip_runtime.h>
#include <cmath>

#define NT    8192      // B*N tokens
#define DIM_  1024
#define EXP_  7168
#define CD_   5120      // concat dim (4096 mlp + 1024 attn)
#define OD_   2048
#define MPAD  8704      // 68 row-tiles of 128 (8192 + worst-case group padding)
#define NRT   68        // row tiles in sorted/padded space

typedef __attribute__((ext_vector_type(8))) short short8;
typedef __attribute__((ext_vector_type(4))) float f32x4;
typedef __attribute__((ext_vector_type(4))) unsigned short ushort4_t;

__device__ __forceinline__ unsigned short f2bf(float f) {
  union { float f; unsigned u; } v; v.f = f;
  return (unsigned short)((v.u + 0x7FFFu + ((v.u >> 16) & 1u)) >> 16);
}
__device__ __forceinline__ float bf2f(unsigned short u) {
  union { unsigned u; float f; } v; v.u = ((unsigned)u) << 16;
  return v.f;
}

#define MFMA16(a, b, c) __builtin_amdgcn_mfma_f32_16x16x32_bf16(a, b, c, 0, 0, 0)

// ======== expert sort: count -> scan -> fill -> scatter (all tiny) ========
__global__ __launch_bounds__(256) void count_experts(const int* __restrict__ em,
                                                     int* __restrict__ blockCnt) {
  __shared__ int h[4];
  int tid = threadIdx.x;
  if (tid < 4) h[tid] = 0;
  __syncthreads();
  atomicAdd(&h[em[blockIdx.x * 256 + tid]], 1);
  __syncthreads();
  if (tid < 4) blockCnt[blockIdx.x * 4 + tid] = h[tid];
}

__global__ void scan_make(const int* __restrict__ blockCnt, int* __restrict__ desc) {
  if (threadIdx.x != 0) return;
  int cnt[4] = {0, 0, 0, 0};
  for (int b = 0; b < 32; b++)
    for (int e = 0; e < 4; e++) cnt[e] += blockCnt[b * 4 + e];
  int base[4]; int acc = 0;
  for (int e = 0; e < 4; e++) { base[e] = acc; acc += ((cnt[e] + 127) >> 7) << 7; }
  for (int e = 0; e < 4; e++) { desc[e] = base[e]; desc[4 + e] = cnt[e]; }
  for (int r = 0; r < NRT; r++) {
    int te = -1;
    for (int e = 0; e < 4; e++) {
      int lo = base[e] >> 7;
      int hi = (base[e] + (((cnt[e] + 127) >> 7) << 7)) >> 7;
      if (r >= lo && r < hi) te = e;
    }
    desc[8 + r] = te;
  }
  int run[4];
  for (int e = 0; e < 4; e++) run[e] = base[e];
  for (int b = 0; b < 32; b++)
    for (int e = 0; e < 4; e++) { desc[76 + b * 4 + e] = run[e]; run[e] += blockCnt[b * 4 + e]; }
}

__global__ __launch_bounds__(256) void fill_perm(int* __restrict__ perm) {
  int i = blockIdx.x * 256 + threadIdx.x;
  if (i < MPAD) perm[i] = -1;
}

__global__ __launch_bounds__(256) void scatter_perm(const int* __restrict__ em,
    const int* __restrict__ desc, int* __restrict__ perm, int* __restrict__ pos) {
  __shared__ int wsum[4][4];  // [wave][expert]
  int tid = threadIdx.x;
  int wv = tid >> 6, ln = tid & 63;
  int t = blockIdx.x * 256 + tid;
  int e = em[t];
  int wrank = 0;
#pragma unroll
  for (int k = 0; k < 4; k++) {
    unsigned long long m = __ballot(e == k);
    if (ln == 0) wsum[wv][k] = __popcll(m);
    if (e == k) wrank = __popcll(m & ((1ull << ln) - 1ull));
  }
  __syncthreads();
  int off = desc[76 + blockIdx.x * 4 + e];
  for (int w = 0; w < wv; w++) off += wsum[w][e];
  int p = off + wrank;
  perm[p] = t;
  pos[t] = p;
}

// ---------------- fp32 -> bf16 convert ----------------
__global__ __launch_bounds__(256) void cvt_bf16(const float* __restrict__ in,
                                                unsigned short* __restrict__ out, int n) {
  int i = (blockIdx.x * 256 + threadIdx.x) * 4;
  if (i >= n) return;
  float4 v = *(const float4*)(in + i);
  ushort4_t o;
  o[0] = f2bf(v.x); o[1] = f2bf(v.y); o[2] = f2bf(v.z); o[3] = f2bf(v.w);
  *(ushort4_t*)(out + i) = o;
}

// ---------------- LN1 + expert input mask -> xn bf16 (SORTED rows) ----------------
__global__ __launch_bounds__(256) void ln1_kernel(const float* __restrict__ x,
    const float* __restrict__ w, const float* __restrict__ b,
    const int* __restrict__ emask, const int* __restrict__ pos,
    unsigned short* __restrict__ xn) {
  int wave = threadIdx.x >> 6, lane = threadIdx.x & 63;
  int t = blockIdx.x * 4 + wave;
  const float* xt = x + (size_t)t * DIM_;
  float4 v[4];
  float s = 0.f, s2 = 0.f;
#pragma unroll
  for (int i = 0; i < 4; i++) {
    v[i] = *(const float4*)(xt + i * 256 + lane * 4);
    s  += v[i].x + v[i].y + v[i].z + v[i].w;
    s2 += v[i].x * v[i].x + v[i].y * v[i].y + v[i].z * v[i].z + v[i].w * v[i].w;
  }
#pragma unroll
  for (int o = 1; o < 64; o <<= 1) { s += __shfl_xor(s, o); s2 += __shfl_xor(s2, o); }
  float mu = s * (1.f / 1024.f);
  float rs = rsqrtf(s2 * (1.f / 1024.f) - mu * mu + 1e-5f);
  int din = 1024 >> (3 - emask[t]);
  unsigned short* ot = xn + (size_t)pos[t] * DIM_;
#pragma unroll
  for (int i = 0; i < 4; i++) {
    int c0 = i * 256 + lane * 4;
    float fv[4] = { v[i].x, v[i].y, v[i].z, v[i].w };
    ushort4_t o;
#pragma unroll
    for (int j = 0; j < 4; j++) {
      int c = c0 + j;
      float val = (c < din) ? (fv[j] - mu) * rs * w[c] + b[c] : 0.f;
      o[j] = f2bf(val);
    }
    *(ushort4_t*)(ot + c0) = o;
  }
}

// ---------------- grouped 128x128 bf16 GEMM (expert-aware, split-K for EPI2) ----
// EPI==1: K = 128<<e per row-tile; scatter q/kv to original tokens, cc stays sorted.
// EPI==2: skip col-tiles >= dout=256<<e; split-K=2 via blockIdx.z; z-half writes
//         bf16 partial (NO bias) to out0/out1; reduction fused into final_epi.
template <int EPI, int KK, int NBN>
__global__ __launch_bounds__(256, 3) void gemm_grp(
    const unsigned short* __restrict__ A, const unsigned short* __restrict__ W,
    const float* __restrict__ bias, const int* __restrict__ tdesc,
    const int* __restrict__ perm, unsigned short* __restrict__ out0,
    unsigned short* __restrict__ out1, unsigned short* __restrict__ out2) {
  __shared__ unsigned short lds[16384];          // 32 KiB: As[2][4096] | Bs[2][4096]
  unsigned short* As = lds;
  unsigned short* Bs = lds + 8192;
  const int r = blockIdx.y;
  const int e = tdesc[8 + r];
  if (e < 0) return;                             // pad tile (uniform exit)
  int ntiles, k0;
  if constexpr (EPI == 1) { ntiles = 4 << e; k0 = 0; }          // K = 128<<e
  else { ntiles = (KK / 2) / 32; k0 = (int)blockIdx.z * (KK / 2); }

  const int tid = threadIdx.x;
  const int lane = tid & 63;
  const int wave = tid >> 6;       // 0..3
  const int wm = wave >> 1, wn = wave & 1;
  const int lg = lane >> 4, lr = lane & 15;

  // XCD swizzle on col dim (NBN % 8 == 0)
  constexpr int CPX = NBN >> 3;
  const int bx = (int)blockIdx.x;
  const int bn = (bx & 7) * CPX + (bx >> 3);
  const int n0 = bn * 128;
  if constexpr (EPI == 2) {
    if (n0 >= (256 << e)) return;                // masked-out output cols (uniform)
  }
  const int m0 = r * 128;

  // staging source map (inverse of superrow XOR swizzle)
  const int s0g = tid >> 3,        s1g = (256 + tid) >> 3;
  const int lc0 = (tid & 7) ^ (s0g & 7), lc1 = (tid & 7) ^ (s1g & 7);
  const int row0 = 2 * s0g + (lc0 >> 2), kc0 = lc0 & 3;
  const int row1 = 2 * s1g + (lc1 >> 2), kc1 = lc1 & 3;
  const unsigned short* aS0 = A + (size_t)(m0 + row0) * KK + k0 + kc0 * 8;
  const unsigned short* aS1 = A + (size_t)(m0 + row1) * KK + k0 + kc1 * 8;
  const unsigned short* bS0 = W + (size_t)(n0 + row0) * KK + k0 + kc0 * 8;
  const unsigned short* bS1 = W + (size_t)(n0 + row1) * KK + k0 + kc1 * 8;

#define GLD(SRC, DST)                                                                \
  __builtin_amdgcn_global_load_lds(                                                  \
      (const __attribute__((address_space(1))) void*)(SRC),                          \
      (__attribute__((address_space(3))) void*)(DST), 16, 0, 0)
#define STAGE(T, SLOT) {                                                             \
    GLD(aS0 + (size_t)(T) * 32, As + (SLOT) * 4096 + tid * 8);                       \
    GLD(aS1 + (size_t)(T) * 32, As + (SLOT) * 4096 + 2048 + tid * 8);                \
    GLD(bS0 + (size_t)(T) * 32, Bs + (SLOT) * 4096 + tid * 8);                       \
    GLD(bS1 + (size_t)(T) * 32, Bs + (SLOT) * 4096 + 2048 + tid * 8);                \
  }

  const int fb = (lr >> 1) * 128 + ((((lr & 1) << 2) + lg) ^ ((lr >> 1) & 7)) * 16;
  const char* apb = (const char*)As + wm * 4096 + fb;
  const char* bpb = (const char*)Bs + wn * 4096 + fb;

  short8 afr[4], bfr[4];
#define LDFRAG(C)                                                                    \
  _Pragma("unroll") for (int mi = 0; mi < 4; mi++)                                   \
    afr[mi] = *(const short8*)(apb + (C) * 8192 + mi * 1024);                        \
  _Pragma("unroll") for (int ni = 0; ni < 4; ni++)                                   \
    bfr[ni] = *(const short8*)(bpb + (C) * 8192 + ni * 1024);

  f32x4 acc[4][4];
  f32x4 zf = { 0.f, 0.f, 0.f, 0.f };
#pragma unroll
  for (int i = 0; i < 4; i++)
#pragma unroll
    for (int j = 0; j < 4; j++) acc[i][j] = zf;

  STAGE(0, 0)
  STAGE(1, 1)
  asm volatile("s_waitcnt vmcnt(4)" ::: "memory");
  __builtin_amdgcn_s_barrier();

#pragma unroll 1
  for (int t = 0; t < ntiles; ++t) {
    const int c = t & 1;
    LDFRAG(c)
    asm volatile("s_waitcnt lgkmcnt(0)" ::: "memory");
    __builtin_amdgcn_sched_barrier(0);
    __builtin_amdgcn_s_barrier();
    const int t2 = (t + 2 < ntiles) ? t + 2 : t;
    STAGE(t2, c)
    __builtin_amdgcn_s_setprio(1);
#pragma unroll
    for (int mi = 0; mi < 4; mi++)
#pragma unroll
      for (int ni = 0; ni < 4; ni++)
        acc[mi][ni] = MFMA16(afr[mi], bfr[ni], acc[mi][ni]);
    __builtin_amdgcn_s_setprio(0);
    asm volatile("s_waitcnt vmcnt(4)" ::: "memory");
    __builtin_amdgcn_s_barrier();
  }
  asm volatile("s_waitcnt vmcnt(0)" ::: "memory");

  // epilogue
#pragma unroll
  for (int mi = 0; mi < 4; mi++) {
#pragma unroll
    for (int ni = 0; ni < 4; ni++) {
#pragma unroll
      for (int rr = 0; rr < 4; rr++) {
        int grow = m0 + wm * 64 + mi * 16 + lg * 4 + rr;
        int gcol = n0 + wn * 64 + ni * 16 + lr;
        float v = acc[mi][ni][rr];
        if constexpr (EPI == 1) {
          int tk = perm[grow];                 // original token (-1 = pad row)
          float bv = bias[gcol & 4095];
          v += (gcol < 4096) ? bv : 0.f;
          if (gcol < 1024) {
            if (tk >= 0) {
              int bb = tk >> 10, n = tk & 1023, h = gcol >> 6, d = gcol & 63;
              out0[(((size_t)(bb * 16 + h) * 1024 + n) << 6) + d] = f2bf(v * 0.125f);
            }
          } else if (gcol < 3072) {
            if (tk >= 0) out1[(size_t)tk * OD_ + (gcol - 1024)] = f2bf(v);
          } else {
            float g = 0.5f * v * (1.f + erff(v * 0.70710678f));
            out2[(size_t)grow * CD_ + (gcol - 3072)] = f2bf(g);   // cc stays sorted
          }
        } else {
          unsigned short* dst = blockIdx.z ? out1 : out0;         // bf16 partial, no bias
          dst[(size_t)grow * OD_ + gcol] = f2bf(v);
        }
      }
    }
  }
#undef GLD
#undef STAGE
#undef LDFRAG
}

// ---------------- LN2 over 2048 -> k (head-major bf16), v (row-major bf16) ------
__global__ __launch_bounds__(256) void ln2_kernel(const unsigned short* __restrict__ kv,
    const float* __restrict__ w, const float* __restrict__ b,
    unsigned short* __restrict__ kb, unsigned short* __restrict__ vrm) {
  int wave = threadIdx.x >> 6, lane = threadIdx.x & 63;
  int t = blockIdx.x * 4 + wave;
  const unsigned short* p = kv + (size_t)t * OD_;
  float vals[4][8];
  float s = 0.f, s2 = 0.f;
#pragma unroll
  for (int i = 0; i < 4; i++) {
    short8 v = *(const short8*)(p + i * 512 + lane * 8);
#pragma unroll
    for (int j = 0; j < 8; j++) {
      float f = bf2f((unsigned short)v[j]);
      vals[i][j] = f; s += f; s2 += f * f;
    }
  }
#pragma unroll
  for (int o = 1; o < 64; o <<= 1) { s += __shfl_xor(s, o); s2 += __shfl_xor(s2, o); }
  float mu = s * (1.f / 2048.f);
  float rs = rsqrtf(s2 * (1.f / 2048.f) - mu * mu + 1e-5f);
  int bidx = t >> 10, n = t & 1023;
#pragma unroll
  for (int i = 0; i < 4; i++) {
    int c0 = i * 512 + lane * 8;
    short8 o8;
#pragma unroll
    for (int j = 0; j < 8; j++) {
      int c = c0 + j;
      o8[j] = (short)f2bf((vals[i][j] - mu) * rs * w[c] + b[c]);
    }
    if (c0 < 1024) {
      int h = c0 >> 6, d = c0 & 63;
      *(short8*)(kb + (((size_t)(bidx * 16 + h) * 1024 + n) << 6) + d) = o8;
    } else {
      *(short8*)(vrm + (size_t)t * 1024 + (c0 - 1024)) = o8;
    }
  }
}

// ---------------- V transpose: [b,n,h*64+d] -> [b,h,d,n] ----------------
__global__ __launch_bounds__(256) void transpose_v(const unsigned short* __restrict__ vrm,
                                                   unsigned short* __restrict__ vt) {
  int bh = blockIdx.x >> 4;
  int nblk = (blockIdx.x & 15) * 64;
  int b = bh >> 4, h = bh & 15;
  __shared__ unsigned short tile[64][65];
  int tid = threadIdx.x;
  int i = tid >> 2;
  int d0 = (tid & 3) * 16;
  const unsigned short* src = vrm + ((size_t)(b * 1024 + nblk + i)) * 1024 + h * 64 + d0;
  short8 v0 = *(const short8*)(src);
  short8 v1 = *(const short8*)(src + 8);
#pragma unroll
  for (int j = 0; j < 8; j++) {
    tile[d0 + j][i] = (unsigned short)v0[j];
    tile[d0 + 8 + j][i] = (unsigned short)v1[j];
  }
  __syncthreads();
  int d = tid >> 2;
  int i0 = (tid & 3) * 16;
  unsigned short* dst = vt + ((size_t)bh * 64 + d) * 1024 + nblk + i0;
  short8 o0, o1;
#pragma unroll
  for (int j = 0; j < 8; j++) { o0[j] = (short)tile[d][i0 + j]; o1[j] = (short)tile[d][i0 + 8 + j]; }
  *(short8*)dst = o0;
  *(short8*)(dst + 8) = o1;
}

// ---------------- flash attention: 1 wave, 32 q-rows, KV tiles of 32 ----------------
__global__ __launch_bounds__(64) void attn_kernel(const unsigned short* __restrict__ q,
    const unsigned short* __restrict__ k, const unsigned short* __restrict__ vt,
    const int* __restrict__ pos, unsigned short* __restrict__ concat) {
  int bh = blockIdx.x >> 5;
  int q0 = (blockIdx.x & 31) * 32;
  int lane = threadIdx.x;
  int lg = lane >> 4, lr = lane & 15;
  __shared__ unsigned short plds[2][512];
  const unsigned short* qp = q + (size_t)bh * (1024 * 64);
  const unsigned short* kp = k + (size_t)bh * (1024 * 64);
  const unsigned short* vp = vt + (size_t)bh * (64 * 1024);
  short8 qf[2][2];
#pragma unroll
  for (int rb = 0; rb < 2; rb++)
#pragma unroll
    for (int c = 0; c < 2; c++)
      qf[rb][c] = *(const short8*)(qp + (q0 + rb * 16 + lr) * 64 + c * 32 + lg * 8);
  f32x4 zf = { 0.f, 0.f, 0.f, 0.f };
  f32x4 o[2][4];
  float m[2][4], l[2][4];
#pragma unroll
  for (int rb = 0; rb < 2; rb++) {
#pragma unroll
    for (int r = 0; r < 4; r++) { m[rb][r] = -1e30f; l[rb][r] = 0.f; }
#pragma unroll
    for (int nb = 0; nb < 4; nb++) o[rb][nb] = zf;
  }
  for (int kt = 0; kt < 1024; kt += 32) {
    f32x4 s[2][2];
    s[0][0] = zf; s[0][1] = zf; s[1][0] = zf; s[1][1] = zf;
#pragma unroll
    for (int h2 = 0; h2 < 2; h2++) {
      short8 kf0 = *(const short8*)(kp + (kt + h2 * 16 + lr) * 64 + lg * 8);
      short8 kf1 = *(const short8*)(kp + (kt + h2 * 16 + lr) * 64 + 32 + lg * 8);
      s[0][h2] = MFMA16(qf[0][0], kf0, s[0][h2]);
      s[0][h2] = MFMA16(qf[0][1], kf1, s[0][h2]);
      s[1][h2] = MFMA16(qf[1][0], kf0, s[1][h2]);
      s[1][h2] = MFMA16(qf[1][1], kf1, s[1][h2]);
    }
    __syncthreads();
#pragma unroll
    for (int rb = 0; rb < 2; rb++) {
      float mx[4], rsum[4];
#pragma unroll
      for (int r = 0; r < 4; r++) mx[r] = fmaxf(s[rb][0][r], s[rb][1][r]);
#pragma unroll
      for (int ofs = 1; ofs < 16; ofs <<= 1)
#pragma unroll
        for (int r = 0; r < 4; r++) mx[r] = fmaxf(mx[r], __shfl_xor(mx[r], ofs));
#pragma unroll
      for (int r = 0; r < 4; r++) {
        float mn = fmaxf(m[rb][r], mx[r]);
        float al = __expf(m[rb][r] - mn);
        float p0 = __expf(s[rb][0][r] - mn);
        float p1 = __expf(s[rb][1][r] - mn);
        m[rb][r] = mn;
        plds[rb][(lg * 4 + r) * 32 + lr] = f2bf(p0);
        plds[rb][(lg * 4 + r) * 32 + 16 + lr] = f2bf(p1);
        rsum[r] = p0 + p1;
        l[rb][r] *= al;
#pragma unroll
        for (int nb = 0; nb < 4; nb++) o[rb][nb][r] *= al;
      }
#pragma unroll
      for (int ofs = 1; ofs < 16; ofs <<= 1)
#pragma unroll
        for (int r = 0; r < 4; r++) rsum[r] += __shfl_xor(rsum[r], ofs);
#pragma unroll
      for (int r = 0; r < 4; r++) l[rb][r] += rsum[r];
    }
    __syncthreads();
    short8 pf0 = *(const short8*)(&plds[0][lr * 32 + lg * 8]);
    short8 pf1 = *(const short8*)(&plds[1][lr * 32 + lg * 8]);
#pragma unroll
    for (int nb = 0; nb < 4; nb++) {
      short8 vf = *(const short8*)(vp + (nb * 16 + lr) * 1024 + kt + lg * 8);
      o[0][nb] = MFMA16(pf0, vf, o[0][nb]);
      o[1][nb] = MFMA16(pf1, vf, o[1][nb]);
    }
  }
  int b = bh >> 4, h = bh & 15;
#pragma unroll
  for (int rb = 0; rb < 2; rb++)
#pragma unroll
    for (int r = 0; r < 4; r++) {
      int n = q0 + rb * 16 + lg * 4 + r;
      int s = pos[b * 1024 + n];          // write concat at SORTED row
      float inv = 1.f / l[rb][r];
#pragma unroll
      for (int nb = 0; nb < 4; nb++)
        concat[(size_t)s * CD_ + 4096 + h * 64 + nb * 16 + lr] = f2bf(o[rb][nb][r] * inv);
    }
}

// -------- final epilogue: split-K reduce + bias + mask + residual + combine -----
__global__ __launch_bounds__(256) void final_epi(const unsigned short* __restrict__ p0,
    const unsigned short* __restrict__ p1, const float* __restrict__ cbias,
    const float* __restrict__ x, const float* __restrict__ probs,
    const int* __restrict__ emask, const int* __restrict__ pos,
    float* __restrict__ out) {
  int t = blockIdx.x;
  int c = threadIdx.x * 4;
  int dout = 2048 >> (3 - emask[t]);
  float p = probs[t];
  size_t row = (size_t)pos[t] * OD_;
  ushort4_t m0v = *(const ushort4_t*)(p0 + row + c);
  ushort4_t m1v = *(const ushort4_t*)(p1 + row + c);
  ushort4_t a0v = *(const ushort4_t*)(p0 + row + 1024 + c);
  ushort4_t a1v = *(const ushort4_t*)(p1 + row + 1024 + c);
  float4 xv = *(const float4*)(x + (size_t)t * 1024 + c);
  float xa[4] = { xv.x, xv.y, xv.z, xv.w };
  float4 o;
  float oa[4];
#pragma unroll
  for (int j = 0; j < 4; j++) {
    float mlp = ((c + j) < dout ? bf2f(m0v[j]) + bf2f(m1v[j]) + cbias[c + j] : 0.f) + xa[j];
    float att = ((1024 + c + j) < dout ?
                 bf2f(a0v[j]) + bf2f(a1v[j]) + cbias[1024 + c + j] : 0.f) + xa[j];
    oa[j] = att + p * mlp;
  }
  o.x = oa[0]; o.y = oa[1]; o.z = oa[2]; o.w = oa[3];
  *(float4*)(out + (size_t)t * 1024 + c) = o;
}

extern "C" void kernel_launch(void* const* d_in, const int* in_sizes, int n_in,
                              void* d_out, int out_size, void* d_ws, size_t ws_size,
                              hipStream_t stream) {
  const float* x        = (const float*)d_in[0];
  const float* probs    = (const float*)d_in[1];
  const float* we       = (const float*)d_in[2];
  const float* mlp_bias = (const float*)d_in[3];
  const float* wc       = (const float*)d_in[4];
  const float* cbias    = (const float*)d_in[5];
  const float* n1w      = (const float*)d_in[6];
  const float* n1b      = (const float*)d_in[7];
  const float* n2w      = (const float*)d_in[8];
  const float* n2b      = (const float*)d_in[9];
  const int*   emask    = (const int*)d_in[10];
  float* out = (float*)d_out;

  char* ws = (char*)d_ws;
  size_t off = 0;
  auto alloc = [&](size_t bytes) {
    char* p = ws + off;
    off += (bytes + 255) & ~(size_t)255;
    return p;
  };
  unsigned short* we_bf = (unsigned short*)alloc((size_t)EXP_ * DIM_ * 2);
  unsigned short* wc_bf = (unsigned short*)alloc((size_t)OD_ * CD_ * 2);
  unsigned short* xn    = (unsigned short*)alloc((size_t)MPAD * DIM_ * 2); // sorted; reused as vrm
  unsigned short* qb    = (unsigned short*)alloc((size_t)NT * DIM_ * 2);
  unsigned short* kv    = (unsigned short*)alloc((size_t)MPAD * OD_ * 2);  // orig order
  unsigned short* kb    = (unsigned short*)alloc((size_t)NT * DIM_ * 2);
  unsigned short* vt    = (unsigned short*)alloc((size_t)NT * DIM_ * 2);
  unsigned short* cc    = (unsigned short*)alloc((size_t)MPAD * CD_ * 2);  // sorted
  int* blockCnt         = (int*)alloc(32 * 4 * 4);
  int* desc             = (int*)alloc(256 * 4);
  int* perm             = (int*)alloc(MPAD * 4);
  int* pos              = (int*)alloc(NT * 4);
  unsigned short* vrm = xn;
  // split-K partials: overlay the xn..vt region (17.8+16.8+35.6+16.8+16.8 MB =
  // 103.8 MB, all dead after attn); need 2 x MPAD*OD_*2 = 71.3 MB. cc untouched.
  unsigned short* pk0 = xn;
  unsigned short* pk1 = xn + (size_t)MPAD * OD_;
  if (off > ws_size) return;  // insufficient workspace -> visible failure, no OOB

  count_experts<<<32, 256, 0, stream>>>(emask, blockCnt);
  scan_make<<<1, 64, 0, stream>>>(blockCnt, desc);
  fill_perm<<<34, 256, 0, stream>>>(perm);
  scatter_perm<<<32, 256, 0, stream>>>(emask, desc, perm, pos);

  cvt_bf16<<<7168, 256, 0, stream>>>(we, we_bf, EXP_ * DIM_);
  cvt_bf16<<<10240, 256, 0, stream>>>(wc, wc_bf, OD_ * CD_);
  ln1_kernel<<<2048, 256, 0, stream>>>(x, n1w, n1b, emask, pos, xn);
  gemm_grp<1, 1024, 56><<<dim3(56, NRT), 256, 0, stream>>>(xn, we_bf, mlp_bias, desc,
                                                           perm, qb, kv, cc);
  ln2_kernel<<<2048, 256, 0, stream>>>(kv, n2w, n2b, kb, vrm);
  transpose_v<<<2048, 256, 0, stream>>>(vrm, vt);
  attn_kernel<<<4096, 64, 0, stream>>>(qb, kb, vt, pos, cc);
  gemm_grp<2, 5120, 16><<<dim3(16, NRT, 2), 256, 0, stream>>>(cc, wc_bf, cbias, desc,
                                                              perm, pk0, pk1, nullptr);
  final_epi<<<8192, 256, 0, stream>>>(pk0, pk1, cbias, x, probs, emask, pos, out);
}

// Round 9
// 560.949 us; speedup vs baseline: 1.0911x; 1.0015x over previous
//
#include <hip/hip_runtime.h>
#include <cmath>

#define NT    8192      // B*N tokens
#define DIM_  1024
#define EXP_  7168
#define CD_   5120      // concat dim (4096 mlp + 1024 attn)
#define OD_   2048
#define MPAD  8704      // 68 row-tiles of 128 (8192 + worst-case group padding)
#define NRT   68        // row tiles in sorted/padded space

typedef __attribute__((ext_vector_type(8))) short short8;
typedef __attribute__((ext_vector_type(4))) float f32x4;
typedef __attribute__((ext_vector_type(4))) unsigned short ushort4_t;

__device__ __forceinline__ unsigned short f2bf(float f) {
  union { float f; unsigned u; } v; v.f = f;
  return (unsigned short)((v.u + 0x7FFFu + ((v.u >> 16) & 1u)) >> 16);
}
__device__ __forceinline__ float bf2f(unsigned short u) {
  union { unsigned u; float f; } v; v.u = ((unsigned)u) << 16;
  return v.f;
}

#define MFMA16(a, b, c) __builtin_amdgcn_mfma_f32_16x16x32_bf16(a, b, c, 0, 0, 0)

// ======== expert sort: count -> scan -> fill -> scatter (all tiny) ========
__global__ __launch_bounds__(256) void count_experts(const int* __restrict__ em,
                                                     int* __restrict__ blockCnt) {
  __shared__ int h[4];
  int tid = threadIdx.x;
  if (tid < 4) h[tid] = 0;
  __syncthreads();
  atomicAdd(&h[em[blockIdx.x * 256 + tid]], 1);
  __syncthreads();
  if (tid < 4) blockCnt[blockIdx.x * 4 + tid] = h[tid];
}

__global__ void scan_make(const int* __restrict__ blockCnt, int* __restrict__ desc) {
  if (threadIdx.x != 0) return;
  int cnt[4] = {0, 0, 0, 0};
  for (int b = 0; b < 32; b++)
    for (int e = 0; e < 4; e++) cnt[e] += blockCnt[b * 4 + e];
  int base[4]; int acc = 0;
  for (int e = 0; e < 4; e++) { base[e] = acc; acc += ((cnt[e] + 127) >> 7) << 7; }
  for (int e = 0; e < 4; e++) { desc[e] = base[e]; desc[4 + e] = cnt[e]; }
  for (int r = 0; r < NRT; r++) {
    int te = -1;
    for (int e = 0; e < 4; e++) {
      int lo = base[e] >> 7;
      int hi = (base[e] + (((cnt[e] + 127) >> 7) << 7)) >> 7;
      if (r >= lo && r < hi) te = e;
    }
    desc[8 + r] = te;
  }
  int run[4];
  for (int e = 0; e < 4; e++) run[e] = base[e];
  for (int b = 0; b < 32; b++)
    for (int e = 0; e < 4; e++) { desc[76 + b * 4 + e] = run[e]; run[e] += blockCnt[b * 4 + e]; }
}

__global__ __launch_bounds__(256) void fill_perm(int* __restrict__ perm) {
  int i = blockIdx.x * 256 + threadIdx.x;
  if (i < MPAD) perm[i] = -1;
}

__global__ __launch_bounds__(256) void scatter_perm(const int* __restrict__ em,
    const int* __restrict__ desc, int* __restrict__ perm, int* __restrict__ pos) {
  __shared__ int wsum[4][4];  // [wave][expert]
  int tid = threadIdx.x;
  int wv = tid >> 6, ln = tid & 63;
  int t = blockIdx.x * 256 + tid;
  int e = em[t];
  int wrank = 0;
#pragma unroll
  for (int k = 0; k < 4; k++) {
    unsigned long long m = __ballot(e == k);
    if (ln == 0) wsum[wv][k] = __popcll(m);
    if (e == k) wrank = __popcll(m & ((1ull << ln) - 1ull));
  }
  __syncthreads();
  int off = desc[76 + blockIdx.x * 4 + e];
  for (int w = 0; w < wv; w++) off += wsum[w][e];
  int p = off + wrank;
  perm[p] = t;
  pos[t] = p;
}

// ---------------- fp32 -> bf16 convert ----------------
__global__ __launch_bounds__(256) void cvt_bf16(const float* __restrict__ in,
                                                unsigned short* __restrict__ out, int n) {
  int i = (blockIdx.x * 256 + threadIdx.x) * 4;
  if (i >= n) return;
  float4 v = *(const float4*)(in + i);
  ushort4_t o;
  o[0] = f2bf(v.x); o[1] = f2bf(v.y); o[2] = f2bf(v.z); o[3] = f2bf(v.w);
  *(ushort4_t*)(out + i) = o;
}

// ---------------- LN1 + expert input mask -> xn bf16 (SORTED rows) ----------------
__global__ __launch_bounds__(256) void ln1_kernel(const float* __restrict__ x,
    const float* __restrict__ w, const float* __restrict__ b,
    const int* __restrict__ emask, const int* __restrict__ pos,
    unsigned short* __restrict__ xn) {
  int wave = threadIdx.x >> 6, lane = threadIdx.x & 63;
  int t = blockIdx.x * 4 + wave;
  const float* xt = x + (size_t)t * DIM_;
  float4 v[4];
  float s = 0.f, s2 = 0.f;
#pragma unroll
  for (int i = 0; i < 4; i++) {
    v[i] = *(const float4*)(xt + i * 256 + lane * 4);
    s  += v[i].x + v[i].y + v[i].z + v[i].w;
    s2 += v[i].x * v[i].x + v[i].y * v[i].y + v[i].z * v[i].z + v[i].w * v[i].w;
  }
#pragma unroll
  for (int o = 1; o < 64; o <<= 1) { s += __shfl_xor(s, o); s2 += __shfl_xor(s2, o); }
  float mu = s * (1.f / 1024.f);
  float rs = rsqrtf(s2 * (1.f / 1024.f) - mu * mu + 1e-5f);
  int din = 1024 >> (3 - emask[t]);
  unsigned short* ot = xn + (size_t)pos[t] * DIM_;
#pragma unroll
  for (int i = 0; i < 4; i++) {
    int c0 = i * 256 + lane * 4;
    float fv[4] = { v[i].x, v[i].y, v[i].z, v[i].w };
    ushort4_t o;
#pragma unroll
    for (int j = 0; j < 4; j++) {
      int c = c0 + j;
      float val = (c < din) ? (fv[j] - mu) * rs * w[c] + b[c] : 0.f;
      o[j] = f2bf(val);
    }
    *(ushort4_t*)(ot + c0) = o;
  }
}

// ---- grouped 128x128 bf16 GEMM, 3-slot LDS ring (2-iter prefetch cover) --------
// EPI==1: K = 128<<e per row-tile; scatter q/kv to original tokens, cc stays sorted.
// EPI==2: skip col-tiles >= dout=256<<e; split-K=2 via blockIdx.z -> bf16 partials.
// Ring: iter t reads slot t%3; stages tile t+2 into slot (t+2)%3; ONE barrier/iter.
//   RAW: tile t+1's loads (issued iter t-1) awaited by vmcnt(4) at iter t end ->
//        ~2 iters (~1800 cyc) cover > HBM latency (~900).
//   WAR: slot (t+2)%3 == (t-1)%3; its block-wide reads finished before iter t-1's
//        end barrier (lgkmcnt(0) precedes it); stage issues after that barrier.
template <int EPI, int KK, int NBN>
__global__ __launch_bounds__(256, 3) void gemm_grp(
    const unsigned short* __restrict__ A, const unsigned short* __restrict__ W,
    const float* __restrict__ bias, const int* __restrict__ tdesc,
    const int* __restrict__ perm, unsigned short* __restrict__ out0,
    unsigned short* __restrict__ out1, unsigned short* __restrict__ out2) {
  __shared__ unsigned short lds[24576];          // 48 KiB: As[3][4096] | Bs[3][4096]
  unsigned short* As = lds;
  unsigned short* Bs = lds + 12288;
  const int r = blockIdx.y;
  const int e = tdesc[8 + r];
  if (e < 0) return;                             // pad tile (uniform exit)
  int ntiles, k0;
  if constexpr (EPI == 1) { ntiles = 4 << e; k0 = 0; }          // K = 128<<e
  else { ntiles = (KK / 2) / 32; k0 = (int)blockIdx.z * (KK / 2); }

  const int tid = threadIdx.x;
  const int lane = tid & 63;
  const int wave = tid >> 6;       // 0..3
  const int wm = wave >> 1, wn = wave & 1;
  const int lg = lane >> 4, lr = lane & 15;

  // XCD swizzle on col dim (NBN % 8 == 0)
  constexpr int CPX = NBN >> 3;
  const int bx = (int)blockIdx.x;
  const int bn = (bx & 7) * CPX + (bx >> 3);
  const int n0 = bn * 128;
  if constexpr (EPI == 2) {
    if (n0 >= (256 << e)) return;                // masked-out output cols (uniform)
  }
  const int m0 = r * 128;

  // staging source map (inverse of superrow XOR swizzle)
  const int s0g = tid >> 3,        s1g = (256 + tid) >> 3;
  const int lc0 = (tid & 7) ^ (s0g & 7), lc1 = (tid & 7) ^ (s1g & 7);
  const int row0 = 2 * s0g + (lc0 >> 2), kc0 = lc0 & 3;
  const int row1 = 2 * s1g + (lc1 >> 2), kc1 = lc1 & 3;
  const unsigned short* aS0 = A + (size_t)(m0 + row0) * KK + k0 + kc0 * 8;
  const unsigned short* aS1 = A + (size_t)(m0 + row1) * KK + k0 + kc1 * 8;
  const unsigned short* bS0 = W + (size_t)(n0 + row0) * KK + k0 + kc0 * 8;
  const unsigned short* bS1 = W + (size_t)(n0 + row1) * KK + k0 + kc1 * 8;

#define GLD(SRC, DST)                                                                \
  __builtin_amdgcn_global_load_lds(                                                  \
      (const __attribute__((address_space(1))) void*)(SRC),                          \
      (__attribute__((address_space(3))) void*)(DST), 16, 0, 0)
#define STAGE(T, SLOT) {                                                             \
    GLD(aS0 + (size_t)(T) * 32, As + (SLOT) * 4096 + tid * 8);                       \
    GLD(aS1 + (size_t)(T) * 32, As + (SLOT) * 4096 + 2048 + tid * 8);                \
    GLD(bS0 + (size_t)(T) * 32, Bs + (SLOT) * 4096 + tid * 8);                       \
    GLD(bS1 + (size_t)(T) * 32, Bs + (SLOT) * 4096 + 2048 + tid * 8);                \
  }

  const int fb = (lr >> 1) * 128 + ((((lr & 1) << 2) + lg) ^ ((lr >> 1) & 7)) * 16;
  const char* apb = (const char*)As + wm * 4096 + fb;
  const char* bpb = (const char*)Bs + wn * 4096 + fb;

  short8 afr[4], bfr[4];
#define LDFRAG(SB)                                                                   \
  _Pragma("unroll") for (int mi = 0; mi < 4; mi++)                                   \
    afr[mi] = *(const short8*)(apb + (SB) + mi * 1024);                              \
  _Pragma("unroll") for (int ni = 0; ni < 4; ni++)                                   \
    bfr[ni] = *(const short8*)(bpb + (SB) + ni * 1024);

  f32x4 acc[4][4];
  f32x4 zf = { 0.f, 0.f, 0.f, 0.f };
#pragma unroll
  for (int i = 0; i < 4; i++)
#pragma unroll
    for (int j = 0; j < 4; j++) acc[i][j] = zf;

  // prologue: stage tiles 0,1 into slots 0,1; wait own tile-0 loads; barrier
  STAGE(0, 0)
  STAGE(1, 1)
  asm volatile("s_waitcnt vmcnt(4)" ::: "memory");
  __builtin_amdgcn_s_barrier();

  int sl = 0;        // slot of tile t
  int sl2 = 2;       // slot of tile t+2 == (t-1)%3 (free after iter t-1's barrier)
#pragma unroll 1
  for (int t = 0; t < ntiles; ++t) {
    LDFRAG(sl * 8192)
    asm volatile("s_waitcnt lgkmcnt(0)" ::: "memory");
    __builtin_amdgcn_sched_barrier(0);
    const int t2 = (t + 2 < ntiles) ? t + 2 : ntiles - 1;  // tail: benign restage
    STAGE(t2, sl2)
    __builtin_amdgcn_s_setprio(1);
#pragma unroll
    for (int mi = 0; mi < 4; mi++)
#pragma unroll
      for (int ni = 0; ni < 4; ni++)
        acc[mi][ni] = MFMA16(afr[mi], bfr[ni], acc[mi][ni]);
    __builtin_amdgcn_s_setprio(0);
    asm volatile("s_waitcnt vmcnt(4)" ::: "memory");   // own tile-(t+1) loads done
    __builtin_amdgcn_s_barrier();                      // block-wide ready + WAR fence
    sl = (sl == 2) ? 0 : sl + 1;
    sl2 = (sl2 == 2) ? 0 : sl2 + 1;
  }
  asm volatile("s_waitcnt vmcnt(0)" ::: "memory");

  // epilogue
#pragma unroll
  for (int mi = 0; mi < 4; mi++) {
#pragma unroll
    for (int ni = 0; ni < 4; ni++) {
#pragma unroll
      for (int rr = 0; rr < 4; rr++) {
        int grow = m0 + wm * 64 + mi * 16 + lg * 4 + rr;
        int gcol = n0 + wn * 64 + ni * 16 + lr;
        float v = acc[mi][ni][rr];
        if constexpr (EPI == 1) {
          int tk = perm[grow];                 // original token (-1 = pad row)
          float bv = bias[gcol & 4095];
          v += (gcol < 4096) ? bv : 0.f;
          if (gcol < 1024) {
            if (tk >= 0) {
              int bb = tk >> 10, n = tk & 1023, h = gcol >> 6, d = gcol & 63;
              out0[(((size_t)(bb * 16 + h) * 1024 + n) << 6) + d] = f2bf(v * 0.125f);
            }
          } else if (gcol < 3072) {
            if (tk >= 0) out1[(size_t)tk * OD_ + (gcol - 1024)] = f2bf(v);
          } else {
            float g = 0.5f * v * (1.f + erff(v * 0.70710678f));
            out2[(size_t)grow * CD_ + (gcol - 3072)] = f2bf(g);   // cc stays sorted
          }
        } else {
          unsigned short* dst = blockIdx.z ? out1 : out0;         // bf16 partial, no bias
          dst[(size_t)grow * OD_ + gcol] = f2bf(v);
        }
      }
    }
  }
#undef GLD
#undef STAGE
#undef LDFRAG
}

// ---------------- LN2 over 2048 -> k (head-major bf16), v (row-major bf16) ------
__global__ __launch_bounds__(256) void ln2_kernel(const unsigned short* __restrict__ kv,
    const float* __restrict__ w, const float* __restrict__ b,
    unsigned short* __restrict__ kb, unsigned short* __restrict__ vrm) {
  int wave = threadIdx.x >> 6, lane = threadIdx.x & 63;
  int t = blockIdx.x * 4 + wave;
  const unsigned short* p = kv + (size_t)t * OD_;
  float vals[4][8];
  float s = 0.f, s2 = 0.f;
#pragma unroll
  for (int i = 0; i < 4; i++) {
    short8 v = *(const short8*)(p + i * 512 + lane * 8);
#pragma unroll
    for (int j = 0; j < 8; j++) {
      float f = bf2f((unsigned short)v[j]);
      vals[i][j] = f; s += f; s2 += f * f;
    }
  }
#pragma unroll
  for (int o = 1; o < 64; o <<= 1) { s += __shfl_xor(s, o); s2 += __shfl_xor(s2, o); }
  float mu = s * (1.f / 2048.f);
  float rs = rsqrtf(s2 * (1.f / 2048.f) - mu * mu + 1e-5f);
  int bidx = t >> 10, n = t & 1023;
#pragma unroll
  for (int i = 0; i < 4; i++) {
    int c0 = i * 512 + lane * 8;
    short8 o8;
#pragma unroll
    for (int j = 0; j < 8; j++) {
      int c = c0 + j;
      o8[j] = (short)f2bf((vals[i][j] - mu) * rs * w[c] + b[c]);
    }
    if (c0 < 1024) {
      int h = c0 >> 6, d = c0 & 63;
      *(short8*)(kb + (((size_t)(bidx * 16 + h) * 1024 + n) << 6) + d) = o8;
    } else {
      *(short8*)(vrm + (size_t)t * 1024 + (c0 - 1024)) = o8;
    }
  }
}

// ---------------- V transpose: [b,n,h*64+d] -> [b,h,d,n] ----------------
__global__ __launch_bounds__(256) void transpose_v(const unsigned short* __restrict__ vrm,
                                                   unsigned short* __restrict__ vt) {
  int bh = blockIdx.x >> 4;
  int nblk = (blockIdx.x & 15) * 64;
  int b = bh >> 4, h = bh & 15;
  __shared__ unsigned short tile[64][65];
  int tid = threadIdx.x;
  int i = tid >> 2;
  int d0 = (tid & 3) * 16;
  const unsigned short* src = vrm + ((size_t)(b * 1024 + nblk + i)) * 1024 + h * 64 + d0;
  short8 v0 = *(const short8*)(src);
  short8 v1 = *(const short8*)(src + 8);
#pragma unroll
  for (int j = 0; j < 8; j++) {
    tile[d0 + j][i] = (unsigned short)v0[j];
    tile[d0 + 8 + j][i] = (unsigned short)v1[j];
  }
  __syncthreads();
  int d = tid >> 2;
  int i0 = (tid & 3) * 16;
  unsigned short* dst = vt + ((size_t)bh * 64 + d) * 1024 + nblk + i0;
  short8 o0, o1;
#pragma unroll
  for (int j = 0; j < 8; j++) { o0[j] = (short)tile[d][i0 + j]; o1[j] = (short)tile[d][i0 + 8 + j]; }
  *(short8*)dst = o0;
  *(short8*)(dst + 8) = o1;
}

// ---------------- flash attention: 1 wave, 32 q-rows, KV tiles of 32 ----------------
__global__ __launch_bounds__(64) void attn_kernel(const unsigned short* __restrict__ q,
    const unsigned short* __restrict__ k, const unsigned short* __restrict__ vt,
    const int* __restrict__ pos, unsigned short* __restrict__ concat) {
  int bh = blockIdx.x >> 5;
  int q0 = (blockIdx.x & 31) * 32;
  int lane = threadIdx.x;
  int lg = lane >> 4, lr = lane & 15;
  __shared__ unsigned short plds[2][512];
  const unsigned short* qp = q + (size_t)bh * (1024 * 64);
  const unsigned short* kp = k + (size_t)bh * (1024 * 64);
  const unsigned short* vp = vt + (size_t)bh * (64 * 1024);
  short8 qf[2][2];
#pragma unroll
  for (int rb = 0; rb < 2; rb++)
#pragma unroll
    for (int c = 0; c < 2; c++)
      qf[rb][c] = *(const short8*)(qp + (q0 + rb * 16 + lr) * 64 + c * 32 + lg * 8);
  f32x4 zf = { 0.f, 0.f, 0.f, 0.f };
  f32x4 o[2][4];
  float m[2][4], l[2][4];
#pragma unroll
  for (int rb = 0; rb < 2; rb++) {
#pragma unroll
    for (int r = 0; r < 4; r++) { m[rb][r] = -1e30f; l[rb][r] = 0.f; }
#pragma unroll
    for (int nb = 0; nb < 4; nb++) o[rb][nb] = zf;
  }
  for (int kt = 0; kt < 1024; kt += 32) {
    f32x4 s[2][2];
    s[0][0] = zf; s[0][1] = zf; s[1][0] = zf; s[1][1] = zf;
#pragma unroll
    for (int h2 = 0; h2 < 2; h2++) {
      short8 kf0 = *(const short8*)(kp + (kt + h2 * 16 + lr) * 64 + lg * 8);
      short8 kf1 = *(const short8*)(kp + (kt + h2 * 16 + lr) * 64 + 32 + lg * 8);
      s[0][h2] = MFMA16(qf[0][0], kf0, s[0][h2]);
      s[0][h2] = MFMA16(qf[0][1], kf1, s[0][h2]);
      s[1][h2] = MFMA16(qf[1][0], kf0, s[1][h2]);
      s[1][h2] = MFMA16(qf[1][1], kf1, s[1][h2]);
    }
    __syncthreads();
#pragma unroll
    for (int rb = 0; rb < 2; rb++) {
      float mx[4], rsum[4];
#pragma unroll
      for (int r = 0; r < 4; r++) mx[r] = fmaxf(s[rb][0][r], s[rb][1][r]);
#pragma unroll
      for (int ofs = 1; ofs < 16; ofs <<= 1)
#pragma unroll
        for (int r = 0; r < 4; r++) mx[r] = fmaxf(mx[r], __shfl_xor(mx[r], ofs));
#pragma unroll
      for (int r = 0; r < 4; r++) {
        float mn = fmaxf(m[rb][r], mx[r]);
        float al = __expf(m[rb][r] - mn);
        float p0 = __expf(s[rb][0][r] - mn);
        float p1 = __expf(s[rb][1][r] - mn);
        m[rb][r] = mn;
        plds[rb][(lg * 4 + r) * 32 + lr] = f2bf(p0);
        plds[rb][(lg * 4 + r) * 32 + 16 + lr] = f2bf(p1);
        rsum[r] = p0 + p1;
        l[rb][r] *= al;
#pragma unroll
        for (int nb = 0; nb < 4; nb++) o[rb][nb][r] *= al;
      }
#pragma unroll
      for (int ofs = 1; ofs < 16; ofs <<= 1)
#pragma unroll
        for (int r = 0; r < 4; r++) rsum[r] += __shfl_xor(rsum[r], ofs);
#pragma unroll
      for (int r = 0; r < 4; r++) l[rb][r] += rsum[r];
    }
    __syncthreads();
    short8 pf0 = *(const short8*)(&plds[0][lr * 32 + lg * 8]);
    short8 pf1 = *(const short8*)(&plds[1][lr * 32 + lg * 8]);
#pragma unroll
    for (int nb = 0; nb < 4; nb++) {
      short8 vf = *(const short8*)(vp + (nb * 16 + lr) * 1024 + kt + lg * 8);
      o[0][nb] = MFMA16(pf0, vf, o[0][nb]);
      o[1][nb] = MFMA16(pf1, vf, o[1][nb]);
    }
  }
  int b = bh >> 4, h = bh & 15;
#pragma unroll
  for (int rb = 0; rb < 2; rb++)
#pragma unroll
    for (int r = 0; r < 4; r++) {
      int n = q0 + rb * 16 + lg * 4 + r;
      int s = pos[b * 1024 + n];          // write concat at SORTED row
      float inv = 1.f / l[rb][r];
#pragma unroll
      for (int nb = 0; nb < 4; nb++)
        concat[(size_t)s * CD_ + 4096 + h * 64 + nb * 16 + lr] = f2bf(o[rb][nb][r] * inv);
    }
}

// -------- final epilogue: split-K reduce + bias + mask + residual + combine -----
__global__ __launch_bounds__(256) void final_epi(const unsigned short* __restrict__ p0,
    const unsigned short* __restrict__ p1, const float* __restrict__ cbias,
    const float* __restrict__ x, const float* __restrict__ probs,
    const int* __restrict__ emask, const int* __restrict__ pos,
    float* __restrict__ out) {
  int t = blockIdx.x;
  int c = threadIdx.x * 4;
  int dout = 2048 >> (3 - emask[t]);
  float p = probs[t];
  size_t row = (size_t)pos[t] * OD_;
  ushort4_t m0v = *(const ushort4_t*)(p0 + row + c);
  ushort4_t m1v = *(const ushort4_t*)(p1 + row + c);
  ushort4_t a0v = *(const ushort4_t*)(p0 + row + 1024 + c);
  ushort4_t a1v = *(const ushort4_t*)(p1 + row + 1024 + c);
  float4 xv = *(const float4*)(x + (size_t)t * 1024 + c);
  float xa[4] = { xv.x, xv.y, xv.z, xv.w };
  float4 o;
  float oa[4];
#pragma unroll
  for (int j = 0; j < 4; j++) {
    float mlp = ((c + j) < dout ? bf2f(m0v[j]) + bf2f(m1v[j]) + cbias[c + j] : 0.f) + xa[j];
    float att = ((1024 + c + j) < dout ?
                 bf2f(a0v[j]) + bf2f(a1v[j]) + cbias[1024 + c + j] : 0.f) + xa[j];
    oa[j] = att + p * mlp;
  }
  o.x = oa[0]; o.y = oa[1]; o.z = oa[2]; o.w = oa[3];
  *(float4*)(out + (size_t)t * 1024 + c) = o;
}

extern "C" void kernel_launch(void* const* d_in, const int* in_sizes, int n_in,
                              void* d_out, int out_size, void* d_ws, size_t ws_size,
                              hipStream_t stream) {
  const float* x        = (const float*)d_in[0];
  const float* probs    = (const float*)d_in[1];
  const float* we       = (const float*)d_in[2];
  const float* mlp_bias = (const float*)d_in[3];
  const float* wc       = (const float*)d_in[4];
  const float* cbias    = (const float*)d_in[5];
  const float* n1w      = (const float*)d_in[6];
  const float* n1b      = (const float*)d_in[7];
  const float* n2w      = (const float*)d_in[8];
  const float* n2b      = (const float*)d_in[9];
  const int*   emask    = (const int*)d_in[10];
  float* out = (float*)d_out;

  char* ws = (char*)d_ws;
  size_t off = 0;
  auto alloc = [&](size_t bytes) {
    char* p = ws + off;
    off += (bytes + 255) & ~(size_t)255;
    return p;
  };
  unsigned short* we_bf = (unsigned short*)alloc((size_t)EXP_ * DIM_ * 2);
  unsigned short* wc_bf = (unsigned short*)alloc((size_t)OD_ * CD_ * 2);
  unsigned short* xn    = (unsigned short*)alloc((size_t)MPAD * DIM_ * 2); // sorted; reused as vrm
  unsigned short* qb    = (unsigned short*)alloc((size_t)NT * DIM_ * 2);
  unsigned short* kv    = (unsigned short*)alloc((size_t)MPAD * OD_ * 2);  // orig order
  unsigned short* kb    = (unsigned short*)alloc((size_t)NT * DIM_ * 2);
  unsigned short* vt    = (unsigned short*)alloc((size_t)NT * DIM_ * 2);
  unsigned short* cc    = (unsigned short*)alloc((size_t)MPAD * CD_ * 2);  // sorted
  int* blockCnt         = (int*)alloc(32 * 4 * 4);
  int* desc             = (int*)alloc(256 * 4);
  int* perm             = (int*)alloc(MPAD * 4);
  int* pos              = (int*)alloc(NT * 4);
  unsigned short* vrm = xn;
  // split-K partials: overlay the xn..vt region (all dead after attn); need
  // 2 x MPAD*OD_*2 = 71.3 MB of the 103.8 MB region. cc untouched.
  unsigned short* pk0 = xn;
  unsigned short* pk1 = xn + (size_t)MPAD * OD_;
  if (off > ws_size) return;  // insufficient workspace -> visible failure, no OOB

  count_experts<<<32, 256, 0, stream>>>(emask, blockCnt);
  scan_make<<<1, 64, 0, stream>>>(blockCnt, desc);
  fill_perm<<<34, 256, 0, stream>>>(perm);
  scatter_perm<<<32, 256, 0, stream>>>(emask, desc, perm, pos);

  cvt_bf16<<<7168, 256, 0, stream>>>(we, we_bf, EXP_ * DIM_);
  cvt_bf16<<<10240, 256, 0, stream>>>(wc, wc_bf, OD_ * CD_);
  ln1_kernel<<<2048, 256, 0, stream>>>(x, n1w, n1b, emask, pos, xn);
  gemm_grp<1, 1024, 56><<<dim3(56, NRT), 256, 0, stream>>>(xn, we_bf, mlp_bias, desc,
                                                           perm, qb, kv, cc);
  ln2_kernel<<<2048, 256, 0, stream>>>(kv, n2w, n2b, kb, vrm);
  transpose_v<<<2048, 256, 0, stream>>>(vrm, vt);
  attn_kernel<<<4096, 64, 0, stream>>>(qb, kb, vt, pos, cc);
  gemm_grp<2, 5120, 16><<<dim3(16, NRT, 2), 256, 0, stream>>>(cc, wc_bf, cbias, desc,
                                                              perm, pk0, pk1, nullptr);
  final_epi<<<8192, 256, 0, stream>>>(pk0, pk1, cbias, x, probs, emask, pos, out);
}